// Round 5
// baseline (1592.594 us; speedup 1.0000x reference)
//
#include <hip/hip_runtime.h>

#define NN 100000
#define EE 1600000
#define CC 128
#define NP 100032   // padded to 64-row tiles (1563 * 64)
#define NBK 782     // dst buckets of 128 nodes (782*128 = 100096 >= NN)
#define BCAP 2304   // bucket capacity: E/NBK=2046 expected, +5.6 sigma slack
#define DBINS 1024  // degree-sort bins

typedef _Float16 f16;
typedef __attribute__((ext_vector_type(2))) f16 f16x2;
typedef __attribute__((ext_vector_type(4))) f16 f16x4;
typedef __attribute__((ext_vector_type(8))) f16 f16x8;
typedef __attribute__((ext_vector_type(4))) float f32x4;

#define MFMA16(a, b, c) __builtin_amdgcn_mfma_f32_16x16x32_f16(a, b, c, 0, 0, 0)

// x / agg live in SLAB layout: [8 slabs of 16ch][NP rows][16 ch] fp16.
// element (row, ch) at ((ch>>4)*NP + row)*16 + (ch&15).
// Aggregate blocks are slab-pinned (slab = blockIdx&7 -> XCD via round-robin
// dispatch): per-XCD gather working set = 3.2 MB < 4 MB L2 (confirmed R2-R4:
// FETCH 257 -> ~41-51 MB). R3 lesson: NO LDS atomics on the edge path (50x).
// R4 lesson: quad-per-node diverges (max over 16 quads) -> degree-sort nodes.

// ---- phase 1: partition edges into dst-buckets; rank saved from 1st pass ----
__global__ __launch_bounds__(1024) void k_part(const int* __restrict__ src,
                                               const int* __restrict__ dst,
                                               int* __restrict__ bcur,
                                               unsigned* __restrict__ bedge) {
  __shared__ int hist[NBK];
  __shared__ int base[NBK];
  const int t = threadIdx.x;
  for (int i = t; i < NBK; i += 1024) hist[i] = 0;
  __syncthreads();
  const int4* src4 = (const int4*)src;
  const int4* dst4 = (const int4*)dst;
  int4 s[4], d[4];
  int rk[16];
  bool val[4];
#pragma unroll
  for (int w = 0; w < 4; w++) {
    int i4 = blockIdx.x * 4096 + w * 1024 + t;
    val[w] = (i4 < EE / 4);
    if (val[w]) {
      s[w] = src4[i4];
      d[w] = dst4[i4];
      rk[w * 4 + 0] = atomicAdd(&hist[d[w].x >> 7], 1);
      rk[w * 4 + 1] = atomicAdd(&hist[d[w].y >> 7], 1);
      rk[w * 4 + 2] = atomicAdd(&hist[d[w].z >> 7], 1);
      rk[w * 4 + 3] = atomicAdd(&hist[d[w].w >> 7], 1);
    }
  }
  __syncthreads();
  for (int i = t; i < NBK; i += 1024) {
    int c = hist[i];
    base[i] = c ? atomicAdd(&bcur[i], c) : 0;
  }
  __syncthreads();
#pragma unroll
  for (int w = 0; w < 4; w++) {
    if (val[w]) {
      int ss[4] = {s[w].x, s[w].y, s[w].z, s[w].w};
      int dd[4] = {d[w].x, d[w].y, d[w].z, d[w].w};
#pragma unroll
      for (int q = 0; q < 4; q++) {
        int b = dd[q] >> 7;
        int slot = base[b] + rk[w * 4 + q];
        if (slot < BCAP)
          bedge[(size_t)b * BCAP + slot] =
              (unsigned)ss[q] | ((unsigned)(dd[q] & 127) << 17);
      }
    }
  }
}

// ---- bucket-count exclusive scan (one block) -> bbase, off[NN] -------------
__global__ __launch_bounds__(1024) void k_bscan(const int* __restrict__ bcur,
                                                int* __restrict__ bbase,
                                                int* __restrict__ off) {
  __shared__ int sh[1024];
  int t = threadIdx.x;
  int v = (t < NBK) ? min(bcur[t], BCAP) : 0;
  sh[t] = v;
  __syncthreads();
  for (int d = 1; d < 1024; d <<= 1) {
    int a = (t >= d) ? sh[t - d] : 0;
    __syncthreads();
    sh[t] += a;
    __syncthreads();
  }
  if (t < NBK) bbase[t] = sh[t] - v;  // exclusive
  if (t == 1023) off[NN] = sh[1023];  // total (== kept edges)
}

// ---- per-bucket: hist -> node offsets (off) -> CSR fill --------------------
__global__ __launch_bounds__(256) void k_bfill2(const int* __restrict__ bcur,
                                                const int* __restrict__ bbase,
                                                const unsigned* __restrict__ bedge,
                                                int* __restrict__ off,
                                                int* __restrict__ csr) {
  __shared__ int h[128];
  __shared__ int sc[128];
  __shared__ int curs[128];
  const int b = blockIdx.x;
  const int t = threadIdx.x;
  if (t < 128) h[t] = 0;
  __syncthreads();
  const int cnt = min(bcur[b], BCAP);
  const unsigned* be = bedge + (size_t)b * BCAP;
  for (int i = t; i < cnt; i += 256) atomicAdd(&h[(be[i] >> 17) & 127], 1);
  __syncthreads();
  int v = (t < 128) ? h[t] : 0;
  if (t < 128) sc[t] = v;
  __syncthreads();
  for (int d = 1; d < 128; d <<= 1) {
    int a = (t >= d && t < 128) ? sc[t - d] : 0;
    __syncthreads();
    if (t < 128) sc[t] += a;
    __syncthreads();
  }
  if (t < 128) {
    int o = bbase[b] + sc[t] - v;  // exclusive node offset
    int n = b * 128 + t;
    if (n < NN) off[n] = o;
    curs[t] = o;
  }
  __syncthreads();
  for (int i = t; i < cnt; i += 256) {
    unsigned u = be[i];
    int node = (u >> 17) & 127;
    int p = atomicAdd(&curs[node], 1);
    csr[p] = (int)(u & 0x1FFFF);
  }
}

// ---- degree counting-sort (descending): perm[0..NN) = nodes by degree ------
__global__ __launch_bounds__(256) void k_dhist(const int* __restrict__ off,
                                               int* __restrict__ dh) {
  int n = blockIdx.x * 256 + threadIdx.x;
  if (n >= NN) return;
  int deg = off[n + 1] - off[n];
  int key = DBINS - 1 - min(deg, DBINS - 1);  // descending degree
  atomicAdd(&dh[key], 1);
}
__global__ __launch_bounds__(1024) void k_dscan(int* __restrict__ dh) {
  __shared__ int sh[DBINS];
  int t = threadIdx.x;
  int v = dh[t];
  sh[t] = v;
  __syncthreads();
  for (int d = 1; d < DBINS; d <<= 1) {
    int a = (t >= d) ? sh[t - d] : 0;
    __syncthreads();
    sh[t] += a;
    __syncthreads();
  }
  dh[t] = sh[t] - v;  // exclusive base (consumed by scatter)
}
__global__ __launch_bounds__(256) void k_dscatter(const int* __restrict__ off,
                                                  int* __restrict__ dh,
                                                  int* __restrict__ perm) {
  int n = blockIdx.x * 256 + threadIdx.x;
  if (n >= NN) return;
  int deg = off[n + 1] - off[n];
  int key = DBINS - 1 - min(deg, DBINS - 1);
  int p = atomicAdd(&dh[key], 1);
  perm[p] = n;
}

// ------- weight pack: fp32 [k][n] -> fp16 in MFMA B-fragment order ----------
struct WPtrs { const float* w[9]; };
__global__ __launch_bounds__(256) void k_packw(WPtrs wp, f16* __restrict__ out) {
  int t = blockIdx.x * 256 + threadIdx.x;  // 9 * 16384
  int mat = t >> 14;
  int idx = t & 16383;
  int j = idx & 7;
  int lane = (idx >> 3) & 63;
  int ks = (idx >> 9) & 3;
  int nt = idx >> 11;
  int c16 = lane & 15, quad = lane >> 4;
  int k = ks * 32 + quad * 8 + j;
  int n = nt * 16 + c16;
  out[(size_t)mat * 16384 + idx] = (f16)wp.w[mat][k * CC + n];
}

// ---------------- layer-1 aggregate (Cin=3), 4-wide neighbor ILP ------------
__global__ __launch_bounds__(256) void k_agg3(const int* __restrict__ off,
                                              const int* __restrict__ csr,
                                              const float* __restrict__ pos,
                                              float* __restrict__ agg3) {
  int n = blockIdx.x * 256 + threadIdx.x;
  if (n >= NN) return;
  int b = off[n], e = off[n + 1];
  float a0 = 0.f, a1 = 0.f, a2 = 0.f;
  int i = b;
  for (; i + 4 <= e; i += 4) {
    int s0 = csr[i], s1 = csr[i + 1], s2 = csr[i + 2], s3 = csr[i + 3];
    float p00 = pos[s0 * 3 + 0], p01 = pos[s0 * 3 + 1], p02 = pos[s0 * 3 + 2];
    float p10 = pos[s1 * 3 + 0], p11 = pos[s1 * 3 + 1], p12 = pos[s1 * 3 + 2];
    float p20 = pos[s2 * 3 + 0], p21 = pos[s2 * 3 + 1], p22 = pos[s2 * 3 + 2];
    float p30 = pos[s3 * 3 + 0], p31 = pos[s3 * 3 + 1], p32 = pos[s3 * 3 + 2];
    a0 += (p00 + p10) + (p20 + p30);
    a1 += (p01 + p11) + (p21 + p31);
    a2 += (p02 + p12) + (p22 + p32);
  }
  for (; i < e; i++) {
    int s = csr[i];
    a0 += pos[s * 3 + 0];
    a1 += pos[s * 3 + 1];
    a2 += pos[s * 3 + 2];
  }
  float rd = 1.0f / fmaxf((float)(e - b), 1.0f);
  agg3[n * 3 + 0] = a0 * rd;
  agg3[n * 3 + 1] = a1 * rd;
  agg3[n * 3 + 2] = a2 * rd;
}

// ---------------- layer-1 node update (3 -> 128), slab-layout fp16 out ------
__global__ __launch_bounds__(256) void k_node1(
    const float* __restrict__ agg3, const float* __restrict__ pos,
    const float* __restrict__ wl, const float* __restrict__ bl,
    const float* __restrict__ wr, const float* __restrict__ g,
    const float* __restrict__ be, const float* __restrict__ bm,
    const float* __restrict__ bv, f16* __restrict__ x) {
  const int c = threadIdx.x & 127;
  const int np = threadIdx.x >> 7;  // node parity (uniform per wave)
  const float Wl0 = wl[c], Wl1 = wl[CC + c], Wl2 = wl[2 * CC + c];
  const float Wr0 = wr[c], Wr1 = wr[CC + c], Wr2 = wr[2 * CC + c];
  const float sc = g[c] * rsqrtf(bv[c] + 1e-5f);
  const float o0 = be[c] + (bl[c] - bm[c]) * sc;
  const size_t sb = ((size_t)(c >> 4) * NP) * 16 + (c & 15);  // slab base
  const int nbase = blockIdx.x * 256;
  const int nend = min(nbase + 256, NN);
#pragma unroll 4
  for (int n = nbase + np; n < nend; n += 2) {
    float acc = agg3[n * 3 + 0] * Wl0 + agg3[n * 3 + 1] * Wl1 +
                agg3[n * 3 + 2] * Wl2 + pos[n * 3 + 0] * Wr0 +
                pos[n * 3 + 1] * Wr1 + pos[n * 3 + 2] * Wr2;
    x[sb + (size_t)n * 16] = (f16)fmaxf(acc * sc + o0, 0.0f);
  }
}

// -------- aggregate: quad-per-node (degree-sorted), slab-pinned, pipelined --
// block = 64 sorted-order nodes x 4 lanes; slab = blockIdx&7 (-> XCD).
// Lane owns one edge/iter, loads the 16-ch slab row (2x f16x8), accumulates
// in 16 f32 regs. csr idx prefetched 2-ahead (non-temporal: don't evict the
// x slab from L2); row loads issued 1-ahead. Quad shfl-reduce, 32B store.
__global__ __launch_bounds__(256) void k_agg_quad(const int* __restrict__ off,
                                                  const int* __restrict__ csr,
                                                  const int* __restrict__ perm,
                                                  const f16* __restrict__ x,
                                                  f16* __restrict__ agg) {
  const int slab = blockIdx.x & 7;
  const int ns = (blockIdx.x >> 3) * 64 + (threadIdx.x >> 2);
  const int cl = threadIdx.x & 3;
  if (ns >= NN) return;  // no barriers below; divergence safe
  const int n = perm[ns];
  const int b = off[n], e = off[n + 1];
  const f16* xs = x + (size_t)slab * NP * 16;
  float a[16];
#pragma unroll
  for (int j = 0; j < 16; j++) a[j] = 0.f;
  if (e > b) {
    const int last = e - 1;
    int idx = __builtin_nontemporal_load(csr + min(b + cl, last));
    int idxn = __builtin_nontemporal_load(csr + min(b + 4 + cl, last));
    const f16* p0 = xs + (size_t)idx * 16;
    f16x8 va = *(const f16x8*)(p0);
    f16x8 vb = *(const f16x8*)(p0 + 8);
    for (int i = b; i < e; i += 4) {
      const f16* pn = xs + (size_t)idxn * 16;  // next-iter gather (clamped dup
      f16x8 wa = *(const f16x8*)(pn);          //  on tail -> L1 hit, masked)
      f16x8 wb = *(const f16x8*)(pn + 8);
      idxn = __builtin_nontemporal_load(csr + min(i + 8 + cl, last));
      if (i + cl < e) {
#pragma unroll
        for (int j = 0; j < 8; j++) a[j] += (float)va[j];
#pragma unroll
        for (int j = 0; j < 8; j++) a[8 + j] += (float)vb[j];
      }
      va = wa;
      vb = wb;
    }
  }
  // intra-quad reduce (xor 1, 2 stay within the quad)
#pragma unroll
  for (int j = 0; j < 16; j++) {
    a[j] += __shfl_xor(a[j], 1);
    a[j] += __shfl_xor(a[j], 2);
  }
  const float rd = 1.0f / fmaxf((float)(e - b), 1.0f);
  f16x4 o;
#pragma unroll
  for (int j = 0; j < 4; j++) o[j] = (f16)(a[cl * 4 + j] * rd);
  *(f16x4*)(agg + ((size_t)slab * NP + n) * 16 + cl * 4) = o;
}

// ---------------- SAGE MFMA fp16: D = agg@wl + x@wr, BN+ReLU ----------------
__global__ __launch_bounds__(256) void k_sage_mfma(
    const f16* __restrict__ xin, f16* __restrict__ xout,
    const f16* __restrict__ agg, const f16* __restrict__ wl,
    const f16* __restrict__ wr, const float* __restrict__ bl,
    const float* __restrict__ g, const float* __restrict__ be,
    const float* __restrict__ bm, const float* __restrict__ bv) {
  const int lane = threadIdx.x & 63;
  const int wave = threadIdx.x >> 6;
  const int c16 = lane & 15;
  const int quad = lane >> 4;
  const int n0 = blockIdx.x * 64 + wave * 16;
  const int rowX = n0 + c16;
  const int rowA = min(rowX, NN - 1);  // agg rows >= NN are never written
  f32x4 acc[8];
#pragma unroll
  for (int t = 0; t < 8; t++) acc[t] = {0.f, 0.f, 0.f, 0.f};
#pragma unroll
  for (int ks = 0; ks < 4; ks++) {
    const int cb = ks * 32 + quad * 8;  // channel base of this A-fragment
    const size_t sb = ((size_t)(cb >> 4) * NP) * 16 + (cb & 8);
    f16x8 Ax = *(const f16x8*)(xin + sb + (size_t)rowX * 16);
    f16x8 Aa = *(const f16x8*)(agg + sb + (size_t)rowA * 16);
#pragma unroll
    for (int nt = 0; nt < 8; nt++) {
      const size_t wo = (size_t)((nt * 4 + ks) * 64 + lane) * 8;
      f16x8 Bl = *(const f16x8*)(wl + wo);
      f16x8 Br = *(const f16x8*)(wr + wo);
      acc[nt] = MFMA16(Aa, Bl, acc[nt]);
      acc[nt] = MFMA16(Ax, Br, acc[nt]);
    }
  }
#pragma unroll
  for (int nt = 0; nt < 8; nt++) {
    const int col = nt * 16 + c16;
    const float blc = bl[col];
    const float sc = g[col] * rsqrtf(bv[col] + 1e-5f);
    const float mm = bm[col];
    const float bb = be[col];
#pragma unroll
    for (int r = 0; r < 4; r++) {
      const int node = n0 + quad * 4 + r;
      if (node < NN) {
        float yv = fmaxf((acc[nt][r] + blc - mm) * sc + bb, 0.0f);
        xout[((size_t)nt * NP + node) * 16 + c16] = (f16)yv;  // slab nt
      }
    }
  }
}

// -------- fused FC head: out = (relu(x@w1+b1)@w2+b2)@w3+b3, LDS relayout ----
__global__ __launch_bounds__(256) void k_dense_fused(
    const f16* __restrict__ x, const f16* __restrict__ w1,
    const f16* __restrict__ w2, const f16* __restrict__ w3,
    const float* __restrict__ b1, const float* __restrict__ b2,
    const float* __restrict__ b3, float* __restrict__ out) {
  const int lane = threadIdx.x & 63;
  const int wave = threadIdx.x >> 6;
  const int c16 = lane & 15;
  const int quad = lane >> 4;
  const int n0 = blockIdx.x * 64 + wave * 16;
  const int lrow = wave * 16;
  __shared__ f16 sh[64][136];  // +8 pad

  f32x4 acc[8];
#pragma unroll
  for (int t = 0; t < 8; t++) acc[t] = {0.f, 0.f, 0.f, 0.f};
  const int rowX = n0 + c16;
#pragma unroll
  for (int ks = 0; ks < 4; ks++) {
    const int cb = ks * 32 + quad * 8;
    const size_t sb = ((size_t)(cb >> 4) * NP) * 16 + (cb & 8);
    f16x8 Ax = *(const f16x8*)(x + sb + (size_t)rowX * 16);
#pragma unroll
    for (int nt = 0; nt < 8; nt++) {
      f16x8 B = *(const f16x8*)(w1 + (size_t)((nt * 4 + ks) * 64 + lane) * 8);
      acc[nt] = MFMA16(Ax, B, acc[nt]);
    }
  }
#pragma unroll
  for (int nt = 0; nt < 8; nt++) {
    const int col = nt * 16 + c16;
    const float bc = b1[col];
#pragma unroll
    for (int r = 0; r < 4; r++)
      sh[lrow + quad * 4 + r][col] = (f16)fmaxf(acc[nt][r] + bc, 0.0f);
  }
  // FC2 (wave-local rows, no barrier needed)
#pragma unroll
  for (int t = 0; t < 8; t++) acc[t] = {0.f, 0.f, 0.f, 0.f};
#pragma unroll
  for (int ks = 0; ks < 4; ks++) {
    f16x8 Ax = *(const f16x8*)&sh[lrow + c16][ks * 32 + quad * 8];
#pragma unroll
    for (int nt = 0; nt < 8; nt++) {
      f16x8 B = *(const f16x8*)(w2 + (size_t)((nt * 4 + ks) * 64 + lane) * 8);
      acc[nt] = MFMA16(Ax, B, acc[nt]);
    }
  }
#pragma unroll
  for (int nt = 0; nt < 8; nt++) {
    const int col = nt * 16 + c16;
    const float bc = b2[col];
#pragma unroll
    for (int r = 0; r < 4; r++)
      sh[lrow + quad * 4 + r][col] = (f16)(acc[nt][r] + bc);
  }
  // FC3 -> out (fp32)
#pragma unroll
  for (int t = 0; t < 8; t++) acc[t] = {0.f, 0.f, 0.f, 0.f};
#pragma unroll
  for (int ks = 0; ks < 4; ks++) {
    f16x8 Ax = *(const f16x8*)&sh[lrow + c16][ks * 32 + quad * 8];
#pragma unroll
    for (int nt = 0; nt < 8; nt++) {
      f16x8 B = *(const f16x8*)(w3 + (size_t)((nt * 4 + ks) * 64 + lane) * 8);
      acc[nt] = MFMA16(Ax, B, acc[nt]);
    }
  }
#pragma unroll
  for (int nt = 0; nt < 8; nt++) {
    const int col = nt * 16 + c16;
    const float bc = b3[col];
#pragma unroll
    for (int r = 0; r < 4; r++) {
      const int node = n0 + quad * 4 + r;
      if (node < NN) out[(size_t)node * CC + col] = acc[nt][r] + bc;
    }
  }
}

extern "C" void kernel_launch(void* const* d_in, const int* in_sizes, int n_in,
                              void* d_out, int out_size, void* d_ws,
                              size_t ws_size, hipStream_t stream) {
  const float* pos = (const float*)d_in[0];
  const int* ei = (const int*)d_in[1];
  const int* src = ei;
  const int* dst = ei + EE;
  auto P = [&](int i) { return (const float*)d_in[i]; };

  // ws: bcur[NBK] | bbase[NBK] | off[NN+2] | bedge[NBK*BCAP] | csr[E] |
  //     wp16 | xa | xb   (~66 MB). bedge is dead after k_bfill2 -> reuse
  //     its space for the degree-sort scratch (dh[1024] + perm[NN]).
  int* bcur = (int*)d_ws;
  int* bbase = bcur + NBK;
  int* off = bbase + NBK;
  unsigned* bedge = (unsigned*)(off + NN + 2);
  int* csr = (int*)(bedge + (size_t)NBK * BCAP);
  f16* wp16 = (f16*)(csr + EE);
  f16* xa = wp16 + 9 * 16384;
  f16* xb = xa + (size_t)NP * CC;

  int* dh = (int*)bedge;     // reuse (dead after k_bfill2)
  int* perm = dh + DBINS;

  f16* agg = (f16*)d_out;  // scratch until the final dense overwrites d_out

  hipMemsetAsync(bcur, 0, NBK * sizeof(int), stream);

  // CSR build: partition -> bucket scan -> per-bucket offsets+fill
  k_part<<<(EE / 4 + 4095) / 4096, 1024, 0, stream>>>(src, dst, bcur, bedge);
  k_bscan<<<1, 1024, 0, stream>>>(bcur, bbase, off);
  k_bfill2<<<NBK, 256, 0, stream>>>(bcur, bbase, bedge, off, csr);

  // degree counting-sort (descending) -> perm
  hipMemsetAsync(dh, 0, DBINS * sizeof(int), stream);
  k_dhist<<<(NN + 255) / 256, 256, 0, stream>>>(off, dh);
  k_dscan<<<1, DBINS, 0, stream>>>(dh);
  k_dscatter<<<(NN + 255) / 256, 256, 0, stream>>>(off, dh, perm);

  WPtrs wp;
  const int wsrc[9] = {9, 11, 16, 18, 23, 25, 30, 32, 34};
  for (int i = 0; i < 9; i++) wp.w[i] = P(wsrc[i]);
  k_packw<<<(9 * 16384) / 256, 256, 0, stream>>>(wp, wp16);

  // layer 1 (Cin=3): agg3 fp32 in d_out scratch (1.2 MB)
  k_agg3<<<(NN + 255) / 256, 256, 0, stream>>>(off, csr, pos, (float*)d_out);
  k_node1<<<(NN + 255) / 256, 256, 0, stream>>>(
      (const float*)d_out, pos, P(2), P(3), P(4), P(5), P(6), P(7), P(8), xa);

  const int NB = NP / 64;  // 1563
  // layers 2..4: ping-pong xa -> xb -> xa -> xb
  const f16* xi = xa;
  f16* xo = xb;
  for (int l = 1; l < 4; l++) {
    int base = 2 + 7 * l;
    int mat = (l - 1) * 2;
    k_agg_quad<<<NB * 8, 256, 0, stream>>>(off, csr, perm, xi, agg);
    k_sage_mfma<<<NB, 256, 0, stream>>>(xi, xo, agg,
                                        wp16 + (size_t)mat * 16384,
                                        wp16 + (size_t)(mat + 1) * 16384,
                                        P(base + 1), P(base + 3), P(base + 4),
                                        P(base + 5), P(base + 6));
    const f16* t = xi;
    xi = xo;
    xo = (f16*)t;
  }

  // fused FC head
  k_dense_fused<<<NB, 256, 0, stream>>>(xi, wp16 + (size_t)6 * 16384,
                                        wp16 + (size_t)7 * 16384,
                                        wp16 + (size_t)8 * 16384, P(31), P(33),
                                        P(35), (float*)d_out);
}

// Round 6
// 871.648 us; speedup vs baseline: 1.8271x; 1.8271x over previous
//
#include <hip/hip_runtime.h>

#define NN 100000
#define NH 50000    // node half boundary (src < NH -> half 0)
#define EE 1600000
#define CC 128
#define NP 100032   // padded to 64-row tiles (1563 * 64)
#define NBK 782     // dst buckets of 128 nodes (782*128 = 100096 >= NN)
#define BCAP 2304   // bucket capacity: E/NBK=2046 expected, +5.6 sigma slack

typedef _Float16 f16;
typedef __attribute__((ext_vector_type(2))) f16 f16x2;
typedef __attribute__((ext_vector_type(4))) f16 f16x4;
typedef __attribute__((ext_vector_type(8))) f16 f16x8;
typedef __attribute__((ext_vector_type(4))) float f32x4;

#define MFMA16(a, b, c) __builtin_amdgcn_mfma_f32_16x16x32_f16(a, b, c, 0, 0, 0)

// x lives in SLABSET layout: [4 slabsets of 32ch][NP rows][32 ch] fp16.
// element (row, ch) at ((ch>>5)*NP + row)*32 + (ch&31).
// Aggregate classes: (slabset s, src-half h) = blockIdx&7 -> one class per XCD
// (round-robin dispatch). Class working set = 50k rows x 64B = 3.2 MB < 4 MB
// per-XCD L2 (L2-pinning mechanism confirmed R2-R4: FETCH 257 -> ~41 MB), and
// the gather granule is a full 64B coalesced oct-read (R4's 32B granule wasted
// the line interface). Each class writes a PARTIAL sum (pre-scaled by 1/deg,
// f16); sage consumes both partials as two MFMA A-operands (exact f32 accum).
// R3 lesson: NO LDS atomics on edge path. R5 lesson: NO contended global
// atomics (degree-sort removed).

// ---- phase 1: partition edges into dst-buckets; rank saved from 1st pass ----
__global__ __launch_bounds__(1024) void k_part(const int* __restrict__ src,
                                               const int* __restrict__ dst,
                                               int* __restrict__ bcur,
                                               unsigned* __restrict__ bedge) {
  __shared__ int hist[NBK];
  __shared__ int base[NBK];
  const int t = threadIdx.x;
  for (int i = t; i < NBK; i += 1024) hist[i] = 0;
  __syncthreads();
  const int4* src4 = (const int4*)src;
  const int4* dst4 = (const int4*)dst;
  int4 s[4], d[4];
  int rk[16];
  bool val[4];
#pragma unroll
  for (int w = 0; w < 4; w++) {
    int i4 = blockIdx.x * 4096 + w * 1024 + t;
    val[w] = (i4 < EE / 4);
    if (val[w]) {
      s[w] = src4[i4];
      d[w] = dst4[i4];
      rk[w * 4 + 0] = atomicAdd(&hist[d[w].x >> 7], 1);
      rk[w * 4 + 1] = atomicAdd(&hist[d[w].y >> 7], 1);
      rk[w * 4 + 2] = atomicAdd(&hist[d[w].z >> 7], 1);
      rk[w * 4 + 3] = atomicAdd(&hist[d[w].w >> 7], 1);
    }
  }
  __syncthreads();
  for (int i = t; i < NBK; i += 1024) {
    int c = hist[i];
    base[i] = c ? atomicAdd(&bcur[i], c) : 0;
  }
  __syncthreads();
#pragma unroll
  for (int w = 0; w < 4; w++) {
    if (val[w]) {
      int ss[4] = {s[w].x, s[w].y, s[w].z, s[w].w};
      int dd[4] = {d[w].x, d[w].y, d[w].z, d[w].w};
#pragma unroll
      for (int q = 0; q < 4; q++) {
        int b = dd[q] >> 7;
        int slot = base[b] + rk[w * 4 + q];
        if (slot < BCAP)
          bedge[(size_t)b * BCAP + slot] =
              (unsigned)ss[q] | ((unsigned)(dd[q] & 127) << 17);
      }
    }
  }
}

// ---- bucket-count exclusive scan (one block) -> bbase, off[NN] -------------
__global__ __launch_bounds__(1024) void k_bscan(const int* __restrict__ bcur,
                                                int* __restrict__ bbase,
                                                int* __restrict__ off) {
  __shared__ int sh[1024];
  int t = threadIdx.x;
  int v = (t < NBK) ? min(bcur[t], BCAP) : 0;
  sh[t] = v;
  __syncthreads();
  for (int d = 1; d < 1024; d <<= 1) {
    int a = (t >= d) ? sh[t - d] : 0;
    __syncthreads();
    sh[t] += a;
    __syncthreads();
  }
  if (t < NBK) bbase[t] = sh[t] - v;  // exclusive
  if (t == 1023) off[NN] = sh[1023];  // total (== kept edges)
}

// ---- per-bucket: hist -> node offsets (off, m) -> half-split CSR fill ------
// Each node's csr segment stores lo-half srcs (< NH) first, then hi-half.
// m[n] = boundary. Aggregation per half reads a contiguous subrange.
__global__ __launch_bounds__(256) void k_bfill2(const int* __restrict__ bcur,
                                                const int* __restrict__ bbase,
                                                const unsigned* __restrict__ bedge,
                                                int* __restrict__ off,
                                                int* __restrict__ m,
                                                int* __restrict__ csr) {
  __shared__ int h[128];
  __shared__ int hlo[128];
  __shared__ int sc[128];
  __shared__ int clo[128];
  __shared__ int chi[128];
  const int b = blockIdx.x;
  const int t = threadIdx.x;
  if (t < 128) {
    h[t] = 0;
    hlo[t] = 0;
  }
  __syncthreads();
  const int cnt = min(bcur[b], BCAP);
  const unsigned* be = bedge + (size_t)b * BCAP;
  for (int i = t; i < cnt; i += 256) {
    unsigned u = be[i];
    int node = (u >> 17) & 127;
    atomicAdd(&h[node], 1);
    if ((u & 0x1FFFF) < NH) atomicAdd(&hlo[node], 1);
  }
  __syncthreads();
  int v = (t < 128) ? h[t] : 0;
  if (t < 128) sc[t] = v;
  __syncthreads();
  for (int d = 1; d < 128; d <<= 1) {
    int a = (t >= d && t < 128) ? sc[t - d] : 0;
    __syncthreads();
    if (t < 128) sc[t] += a;
    __syncthreads();
  }
  if (t < 128) {
    int o = bbase[b] + sc[t] - v;  // exclusive node offset
    int n = b * 128 + t;
    if (n < NN) {
      off[n] = o;
      m[n] = o + hlo[t];
    }
    clo[t] = o;
    chi[t] = o + hlo[t];
  }
  __syncthreads();
  for (int i = t; i < cnt; i += 256) {
    unsigned u = be[i];
    int node = (u >> 17) & 127;
    int srcn = (int)(u & 0x1FFFF);
    int p = (srcn < NH) ? atomicAdd(&clo[node], 1) : atomicAdd(&chi[node], 1);
    csr[p] = srcn;
  }
}

// ------- weight pack: fp32 [k][n] -> fp16 in MFMA B-fragment order ----------
struct WPtrs { const float* w[9]; };
__global__ __launch_bounds__(256) void k_packw(WPtrs wp, f16* __restrict__ out) {
  int t = blockIdx.x * 256 + threadIdx.x;  // 9 * 16384
  int mat = t >> 14;
  int idx = t & 16383;
  int j = idx & 7;
  int lane = (idx >> 3) & 63;
  int ks = (idx >> 9) & 3;
  int nt = idx >> 11;
  int c16 = lane & 15, quad = lane >> 4;
  int k = ks * 32 + quad * 8 + j;
  int n = nt * 16 + c16;
  out[(size_t)mat * 16384 + idx] = (f16)wp.w[mat][k * CC + n];
}

// ---------------- layer-1 aggregate (Cin=3), 4-wide neighbor ILP ------------
__global__ __launch_bounds__(256) void k_agg3(const int* __restrict__ off,
                                              const int* __restrict__ csr,
                                              const float* __restrict__ pos,
                                              float* __restrict__ agg3) {
  int n = blockIdx.x * 256 + threadIdx.x;
  if (n >= NN) return;
  int b = off[n], e = off[n + 1];
  float a0 = 0.f, a1 = 0.f, a2 = 0.f;
  int i = b;
  for (; i + 4 <= e; i += 4) {
    int s0 = csr[i], s1 = csr[i + 1], s2 = csr[i + 2], s3 = csr[i + 3];
    float p00 = pos[s0 * 3 + 0], p01 = pos[s0 * 3 + 1], p02 = pos[s0 * 3 + 2];
    float p10 = pos[s1 * 3 + 0], p11 = pos[s1 * 3 + 1], p12 = pos[s1 * 3 + 2];
    float p20 = pos[s2 * 3 + 0], p21 = pos[s2 * 3 + 1], p22 = pos[s2 * 3 + 2];
    float p30 = pos[s3 * 3 + 0], p31 = pos[s3 * 3 + 1], p32 = pos[s3 * 3 + 2];
    a0 += (p00 + p10) + (p20 + p30);
    a1 += (p01 + p11) + (p21 + p31);
    a2 += (p02 + p12) + (p22 + p32);
  }
  for (; i < e; i++) {
    int s = csr[i];
    a0 += pos[s * 3 + 0];
    a1 += pos[s * 3 + 1];
    a2 += pos[s * 3 + 2];
  }
  float rd = 1.0f / fmaxf((float)(e - b), 1.0f);
  agg3[n * 3 + 0] = a0 * rd;
  agg3[n * 3 + 1] = a1 * rd;
  agg3[n * 3 + 2] = a2 * rd;
}

// ---------------- layer-1 node update (3 -> 128), slabset-layout out --------
__global__ __launch_bounds__(256) void k_node1(
    const float* __restrict__ agg3, const float* __restrict__ pos,
    const float* __restrict__ wl, const float* __restrict__ bl,
    const float* __restrict__ wr, const float* __restrict__ g,
    const float* __restrict__ be, const float* __restrict__ bm,
    const float* __restrict__ bv, f16* __restrict__ x) {
  const int c = threadIdx.x & 127;
  const int np = threadIdx.x >> 7;  // node parity (uniform per wave)
  const float Wl0 = wl[c], Wl1 = wl[CC + c], Wl2 = wl[2 * CC + c];
  const float Wr0 = wr[c], Wr1 = wr[CC + c], Wr2 = wr[2 * CC + c];
  const float sc = g[c] * rsqrtf(bv[c] + 1e-5f);
  const float o0 = be[c] + (bl[c] - bm[c]) * sc;
  const size_t sb = ((size_t)(c >> 5) * NP) * 32 + (c & 31);  // slabset base
  const int nbase = blockIdx.x * 256;
  const int nend = min(nbase + 256, NN);
#pragma unroll 4
  for (int n = nbase + np; n < nend; n += 2) {
    float acc = agg3[n * 3 + 0] * Wl0 + agg3[n * 3 + 1] * Wl1 +
                agg3[n * 3 + 2] * Wl2 + pos[n * 3 + 0] * Wr0 +
                pos[n * 3 + 1] * Wr1 + pos[n * 3 + 2] * Wr2;
    x[sb + (size_t)n * 32] = (f16)fmaxf(acc * sc + o0, 0.0f);
  }
}

// -------- aggregate: oct-per-node, (slabset, half) class per XCD ------------
// class c = blockIdx&7: s = c>>1 (32-ch slabset), h = c&1 (src half).
// Each oct (8 lanes x 4ch) processes one edge/iter: a coalesced 64B row read,
// L2-resident (3.2 MB class working set). No cross-lane reduce: lane owns its
// 4 channels. Partial sum pre-scaled by 1/deg, stored f16 to p[h].
__global__ __launch_bounds__(256) void k_agg_oct(const int* __restrict__ off,
                                                 const int* __restrict__ m,
                                                 const int* __restrict__ csr,
                                                 const f16* __restrict__ x,
                                                 f16* __restrict__ p0,
                                                 f16* __restrict__ p1) {
  const int c = blockIdx.x & 7;
  const int s = c >> 1;
  const int h = c & 1;
  const int n = (blockIdx.x >> 3) * 32 + (threadIdx.x >> 3);
  const int ol = threadIdx.x & 7;  // 4 channels each
  if (n >= NN) return;  // no barriers below
  const int b0 = off[n], e0 = off[n + 1], mm = m[n];
  const int b = h ? mm : b0;
  const int e = h ? e0 : mm;
  const f16* xs = x + (size_t)s * NP * 32 + ol * 4;
  float a0 = 0.f, a1 = 0.f, a2 = 0.f, a3 = 0.f;
  if (e > b) {
    const int last = e - 1;
    int idx = __builtin_nontemporal_load(csr + b);
    f16x4 v = *(const f16x4*)(xs + (size_t)idx * 32);
    int idxn = __builtin_nontemporal_load(csr + min(b + 1, last));
    for (int i = b; i < e; i++) {
      f16x4 vn = *(const f16x4*)(xs + (size_t)idxn * 32);  // next row (dup on
      int idx2 = __builtin_nontemporal_load(csr + min(i + 2, last));  // tail)
      a0 += (float)v[0];
      a1 += (float)v[1];
      a2 += (float)v[2];
      a3 += (float)v[3];
      v = vn;
      idxn = idx2;
    }
  }
  const float rd = 1.0f / fmaxf((float)(e0 - b0), 1.0f);  // full degree
  f16x4 o;
  o[0] = (f16)(a0 * rd);
  o[1] = (f16)(a1 * rd);
  o[2] = (f16)(a2 * rd);
  o[3] = (f16)(a3 * rd);
  f16* pp = h ? p1 : p0;
  *(f16x4*)(pp + ((size_t)s * NN + n) * 32 + ol * 4) = o;
}

// -------- SAGE MFMA fp16: D = (p0+p1)@wl + x@wr, BN+ReLU --------------------
__global__ __launch_bounds__(256) void k_sage_mfma(
    const f16* __restrict__ xin, f16* __restrict__ xout,
    const f16* __restrict__ p0, const f16* __restrict__ p1,
    const f16* __restrict__ wl, const f16* __restrict__ wr,
    const float* __restrict__ bl, const float* __restrict__ g,
    const float* __restrict__ be, const float* __restrict__ bm,
    const float* __restrict__ bv) {
  const int lane = threadIdx.x & 63;
  const int wave = threadIdx.x >> 6;
  const int c16 = lane & 15;
  const int quad = lane >> 4;
  const int n0 = blockIdx.x * 64 + wave * 16;
  const int rowX = n0 + c16;
  const int rowA = min(rowX, NN - 1);  // partials sized by NN
  f32x4 acc[8];
#pragma unroll
  for (int t = 0; t < 8; t++) acc[t] = {0.f, 0.f, 0.f, 0.f};
#pragma unroll
  for (int ks = 0; ks < 4; ks++) {
    f16x8 Ax = *(const f16x8*)(xin + ((size_t)ks * NP + rowX) * 32 + quad * 8);
    f16x8 A0 = *(const f16x8*)(p0 + ((size_t)ks * NN + rowA) * 32 + quad * 8);
    f16x8 A1 = *(const f16x8*)(p1 + ((size_t)ks * NN + rowA) * 32 + quad * 8);
#pragma unroll
    for (int nt = 0; nt < 8; nt++) {
      const size_t wo = (size_t)((nt * 4 + ks) * 64 + lane) * 8;
      f16x8 Bl = *(const f16x8*)(wl + wo);
      f16x8 Br = *(const f16x8*)(wr + wo);
      acc[nt] = MFMA16(A0, Bl, acc[nt]);
      acc[nt] = MFMA16(A1, Bl, acc[nt]);
      acc[nt] = MFMA16(Ax, Br, acc[nt]);
    }
  }
#pragma unroll
  for (int nt = 0; nt < 8; nt++) {
    const int col = nt * 16 + c16;
    const float blc = bl[col];
    const float sc = g[col] * rsqrtf(bv[col] + 1e-5f);
    const float mm = bm[col];
    const float bb = be[col];
    const size_t ob = ((size_t)(col >> 5) * NP) * 32 + (col & 31);
#pragma unroll
    for (int r = 0; r < 4; r++) {
      const int node = n0 + quad * 4 + r;
      if (node < NN) {
        float yv = fmaxf((acc[nt][r] + blc - mm) * sc + bb, 0.0f);
        xout[ob + (size_t)node * 32] = (f16)yv;
      }
    }
  }
}

// -------- fused FC head: out = (relu(x@w1+b1)@w2+b2)@w3+b3, LDS relayout ----
__global__ __launch_bounds__(256) void k_dense_fused(
    const f16* __restrict__ x, const f16* __restrict__ w1,
    const f16* __restrict__ w2, const f16* __restrict__ w3,
    const float* __restrict__ b1, const float* __restrict__ b2,
    const float* __restrict__ b3, float* __restrict__ out) {
  const int lane = threadIdx.x & 63;
  const int wave = threadIdx.x >> 6;
  const int c16 = lane & 15;
  const int quad = lane >> 4;
  const int n0 = blockIdx.x * 64 + wave * 16;
  const int lrow = wave * 16;
  __shared__ f16 sh[64][136];  // +8 pad

  f32x4 acc[8];
#pragma unroll
  for (int t = 0; t < 8; t++) acc[t] = {0.f, 0.f, 0.f, 0.f};
  const int rowX = n0 + c16;
#pragma unroll
  for (int ks = 0; ks < 4; ks++) {
    f16x8 Ax = *(const f16x8*)(x + ((size_t)ks * NP + rowX) * 32 + quad * 8);
#pragma unroll
    for (int nt = 0; nt < 8; nt++) {
      f16x8 B = *(const f16x8*)(w1 + (size_t)((nt * 4 + ks) * 64 + lane) * 8);
      acc[nt] = MFMA16(Ax, B, acc[nt]);
    }
  }
#pragma unroll
  for (int nt = 0; nt < 8; nt++) {
    const int col = nt * 16 + c16;
    const float bc = b1[col];
#pragma unroll
    for (int r = 0; r < 4; r++)
      sh[lrow + quad * 4 + r][col] = (f16)fmaxf(acc[nt][r] + bc, 0.0f);
  }
  // FC2 (wave-local rows, no barrier needed)
#pragma unroll
  for (int t = 0; t < 8; t++) acc[t] = {0.f, 0.f, 0.f, 0.f};
#pragma unroll
  for (int ks = 0; ks < 4; ks++) {
    f16x8 Ax = *(const f16x8*)&sh[lrow + c16][ks * 32 + quad * 8];
#pragma unroll
    for (int nt = 0; nt < 8; nt++) {
      f16x8 B = *(const f16x8*)(w2 + (size_t)((nt * 4 + ks) * 64 + lane) * 8);
      acc[nt] = MFMA16(Ax, B, acc[nt]);
    }
  }
#pragma unroll
  for (int nt = 0; nt < 8; nt++) {
    const int col = nt * 16 + c16;
    const float bc = b2[col];
#pragma unroll
    for (int r = 0; r < 4; r++)
      sh[lrow + quad * 4 + r][col] = (f16)(acc[nt][r] + bc);
  }
  // FC3 -> out (fp32)
#pragma unroll
  for (int t = 0; t < 8; t++) acc[t] = {0.f, 0.f, 0.f, 0.f};
#pragma unroll
  for (int ks = 0; ks < 4; ks++) {
    f16x8 Ax = *(const f16x8*)&sh[lrow + c16][ks * 32 + quad * 8];
#pragma unroll
    for (int nt = 0; nt < 8; nt++) {
      f16x8 B = *(const f16x8*)(w3 + (size_t)((nt * 4 + ks) * 64 + lane) * 8);
      acc[nt] = MFMA16(Ax, B, acc[nt]);
    }
  }
#pragma unroll
  for (int nt = 0; nt < 8; nt++) {
    const int col = nt * 16 + c16;
    const float bc = b3[col];
#pragma unroll
    for (int r = 0; r < 4; r++) {
      const int node = n0 + quad * 4 + r;
      if (node < NN) out[(size_t)node * CC + col] = acc[nt][r] + bc;
    }
  }
}

extern "C" void kernel_launch(void* const* d_in, const int* in_sizes, int n_in,
                              void* d_out, int out_size, void* d_ws,
                              size_t ws_size, hipStream_t stream) {
  const float* pos = (const float*)d_in[0];
  const int* ei = (const int*)d_in[1];
  const int* src = ei;
  const int* dst = ei + EE;
  auto P = [&](int i) { return (const float*)d_in[i]; };

  // ws: bcur[NBK] | bbase[NBK] | off[NN+2] | bedge[NBK*BCAP] | csr[E] |
  //     wp16 | xa | xb | m[NN]   (~66 MB)
  int* bcur = (int*)d_ws;
  int* bbase = bcur + NBK;
  int* off = bbase + NBK;
  unsigned* bedge = (unsigned*)(off + NN + 2);
  int* csr = (int*)(bedge + (size_t)NBK * BCAP);
  f16* wp16 = (f16*)(csr + EE);
  f16* xa = wp16 + 9 * 16384;
  f16* xb = xa + (size_t)NP * CC;
  int* m = (int*)(xb + (size_t)NP * CC);

  // d_out scratch: two f16 partial-agg buffers (2 x NN x 128 x 2B = 51.2 MB
  // = exactly out_size); consumed by sage before the next layer overwrites.
  f16* p0 = (f16*)d_out;
  f16* p1 = p0 + (size_t)NN * CC;

  hipMemsetAsync(bcur, 0, NBK * sizeof(int), stream);

  // CSR build: partition -> bucket scan -> per-bucket offsets + half-split fill
  k_part<<<(EE / 4 + 4095) / 4096, 1024, 0, stream>>>(src, dst, bcur, bedge);
  k_bscan<<<1, 1024, 0, stream>>>(bcur, bbase, off);
  k_bfill2<<<NBK, 256, 0, stream>>>(bcur, bbase, bedge, off, m, csr);

  WPtrs wp;
  const int wsrc[9] = {9, 11, 16, 18, 23, 25, 30, 32, 34};
  for (int i = 0; i < 9; i++) wp.w[i] = P(wsrc[i]);
  k_packw<<<(9 * 16384) / 256, 256, 0, stream>>>(wp, wp16);

  // layer 1 (Cin=3): agg3 fp32 in d_out scratch (1.2 MB, before partials)
  k_agg3<<<(NN + 255) / 256, 256, 0, stream>>>(off, csr, pos, (float*)d_out);
  k_node1<<<(NN + 255) / 256, 256, 0, stream>>>(
      (const float*)d_out, pos, P(2), P(3), P(4), P(5), P(6), P(7), P(8), xa);

  const int NB = NP / 64;  // 1563
  // layers 2..4: ping-pong xa -> xb -> xa -> xb
  const f16* xi = xa;
  f16* xo = xb;
  for (int l = 1; l < 4; l++) {
    int base = 2 + 7 * l;
    int mat = (l - 1) * 2;
    k_agg_oct<<<(NN / 32) * 8, 256, 0, stream>>>(off, m, csr, xi, p0, p1);
    k_sage_mfma<<<NB, 256, 0, stream>>>(xi, xo, p0, p1,
                                        wp16 + (size_t)mat * 16384,
                                        wp16 + (size_t)(mat + 1) * 16384,
                                        P(base + 1), P(base + 3), P(base + 4),
                                        P(base + 5), P(base + 6));
    const f16* t = xi;
    xi = xo;
    xo = (f16*)t;
  }

  // fused FC head
  k_dense_fused<<<NB, 256, 0, stream>>>(xi, wp16 + (size_t)6 * 16384,
                                        wp16 + (size_t)7 * 16384,
                                        wp16 + (size_t)8 * 16384, P(31), P(33),
                                        P(35), (float*)d_out);
}

// Round 7
// 580.313 us; speedup vs baseline: 2.7444x; 1.5020x over previous
//
#include <hip/hip_runtime.h>

#define NN 100000
#define EE 1600000
#define CC 128
#define NP 100032   // padded to 64-row tiles (1563 * 64)
#define NBK 782     // dst buckets of 128 nodes (782*128 = 100096 >= NN)
#define BCAP 2304   // bucket capacity: E/NBK=2046 expected, +5.6 sigma slack

typedef _Float16 f16;
typedef __attribute__((ext_vector_type(2))) f16 f16x2;
typedef __attribute__((ext_vector_type(8))) f16 f16x8;
typedef __attribute__((ext_vector_type(4))) float f32x4;

#define MFMA16(a, b, c) __builtin_amdgcn_mfma_f32_16x16x32_f16(a, b, c, 0, 0, 0)

// LEDGER (R1-R6): flat [row][128ch] layout + wave-per-node 16-deep gather is
// the aggregate optimum (76 us; beyond-L2 random-fetch wall ~3.4 TB/s).
// Failed: 16ch slabs (wave-latency, R2), LDS atomics (50x, R3), quad/node
// (divergence, R4), degree-sort w/ contended atomics (R5), oct+partials
// (depth-1 serial + write-stream L2 thrash, R6). This round: R1 structure +
// NT hints on csr/agg streams (keep x resident in L2) + de-contended CSR
// build (sub-histograms: /4 in k_part, /8 in k_bfill2).

// ---- phase 1: partition edges into dst-buckets (4 LDS sub-histograms) ------
__global__ __launch_bounds__(1024) void k_part(const int* __restrict__ src,
                                               const int* __restrict__ dst,
                                               int* __restrict__ bcur,
                                               unsigned* __restrict__ bedge) {
  __shared__ int hist[4][NBK];  // pass1: per-substream rank counters; then base
  const int t = threadIdx.x;
  const int s = t & 3;  // sub-stream
  for (int i = t; i < 4 * NBK; i += 1024) ((int*)hist)[i] = 0;
  __syncthreads();
  const int4* src4 = (const int4*)src;
  const int4* dst4 = (const int4*)dst;
  int4 sv[4], dv[4];
  int rk[16];
  bool val[4];
#pragma unroll
  for (int w = 0; w < 4; w++) {
    int i4 = blockIdx.x * 4096 + w * 1024 + t;
    val[w] = (i4 < EE / 4);
    if (val[w]) {
      sv[w] = src4[i4];
      dv[w] = dst4[i4];
      rk[w * 4 + 0] = atomicAdd(&hist[s][dv[w].x >> 7], 1);
      rk[w * 4 + 1] = atomicAdd(&hist[s][dv[w].y >> 7], 1);
      rk[w * 4 + 2] = atomicAdd(&hist[s][dv[w].z >> 7], 1);
      rk[w * 4 + 3] = atomicAdd(&hist[s][dv[w].w >> 7], 1);
    }
  }
  __syncthreads();
  for (int i = t; i < NBK; i += 1024) {
    int c0 = hist[0][i], c1 = hist[1][i], c2 = hist[2][i], c3 = hist[3][i];
    int tot = c0 + c1 + c2 + c3;
    int g = tot ? atomicAdd(&bcur[i], tot) : 0;
    hist[0][i] = g;
    hist[1][i] = g + c0;
    hist[2][i] = g + c0 + c1;
    hist[3][i] = g + c0 + c1 + c2;
  }
  __syncthreads();
#pragma unroll
  for (int w = 0; w < 4; w++) {
    if (val[w]) {
      int ss[4] = {sv[w].x, sv[w].y, sv[w].z, sv[w].w};
      int dd[4] = {dv[w].x, dv[w].y, dv[w].z, dv[w].w};
#pragma unroll
      for (int q = 0; q < 4; q++) {
        int b = dd[q] >> 7;
        int slot = hist[s][b] + rk[w * 4 + q];
        if (slot < BCAP)
          bedge[(size_t)b * BCAP + slot] =
              (unsigned)ss[q] | ((unsigned)(dd[q] & 127) << 17);
      }
    }
  }
}

// ---- bucket-count exclusive scan (one block) -> bbase, off[NN] -------------
__global__ __launch_bounds__(1024) void k_bscan(const int* __restrict__ bcur,
                                                int* __restrict__ bbase,
                                                int* __restrict__ off) {
  __shared__ int sh[1024];
  int t = threadIdx.x;
  int v = (t < NBK) ? min(bcur[t], BCAP) : 0;
  sh[t] = v;
  __syncthreads();
  for (int d = 1; d < 1024; d <<= 1) {
    int a = (t >= d) ? sh[t - d] : 0;
    __syncthreads();
    sh[t] += a;
    __syncthreads();
  }
  if (t < NBK) bbase[t] = sh[t] - v;  // exclusive
  if (t == 1023) off[NN] = sh[1023];  // total (== kept edges)
}

// ---- per-bucket: 8-sub-histogram -> node offsets (off) -> CSR fill ---------
__global__ __launch_bounds__(256) void k_bfill2(const int* __restrict__ bcur,
                                                const int* __restrict__ bbase,
                                                const unsigned* __restrict__ bedge,
                                                int* __restrict__ off,
                                                int* __restrict__ csr) {
  __shared__ int h[8][128];
  __shared__ int sc[128];
  __shared__ int curs[8][128];
  const int b = blockIdx.x;
  const int t = threadIdx.x;
  const int s = t & 7;
  for (int i = t; i < 8 * 128; i += 256) ((int*)h)[i] = 0;
  __syncthreads();
  const int cnt = min(bcur[b], BCAP);
  const unsigned* be = bedge + (size_t)b * BCAP;
  for (int i = t; i < cnt; i += 256) atomicAdd(&h[s][(be[i] >> 17) & 127], 1);
  __syncthreads();
  int tot = 0;
  if (t < 128) {
#pragma unroll
    for (int s2 = 0; s2 < 8; s2++) tot += h[s2][t];
    sc[t] = tot;
  }
  __syncthreads();
  for (int d = 1; d < 128; d <<= 1) {
    int a = (t >= d && t < 128) ? sc[t - d] : 0;
    __syncthreads();
    if (t < 128) sc[t] += a;
    __syncthreads();
  }
  if (t < 128) {
    int o = bbase[b] + sc[t] - tot;  // exclusive node offset
    int n = b * 128 + t;
    if (n < NN) off[n] = o;
    int run = o;
#pragma unroll
    for (int s2 = 0; s2 < 8; s2++) {
      curs[s2][t] = run;
      run += h[s2][t];
    }
  }
  __syncthreads();
  for (int i = t; i < cnt; i += 256) {
    unsigned u = be[i];
    int node = (u >> 17) & 127;
    int p = atomicAdd(&curs[s][node], 1);
    csr[p] = (int)(u & 0x1FFFF);
  }
}

// ------- weight pack: fp32 [k][n] -> fp16 in MFMA B-fragment order ----------
struct WPtrs { const float* w[9]; };
__global__ __launch_bounds__(256) void k_packw(WPtrs wp, f16* __restrict__ out) {
  int t = blockIdx.x * 256 + threadIdx.x;  // 9 * 16384
  int mat = t >> 14;
  int idx = t & 16383;
  int j = idx & 7;
  int lane = (idx >> 3) & 63;
  int ks = (idx >> 9) & 3;
  int nt = idx >> 11;
  int c16 = lane & 15, quad = lane >> 4;
  int k = ks * 32 + quad * 8 + j;
  int n = nt * 16 + c16;
  out[(size_t)mat * 16384 + idx] = (f16)wp.w[mat][k * CC + n];
}

// ---------------- layer-1 aggregate (Cin=3), 4-wide neighbor ILP ------------
__global__ __launch_bounds__(256) void k_agg3(const int* __restrict__ off,
                                              const int* __restrict__ csr,
                                              const float* __restrict__ pos,
                                              float* __restrict__ agg3) {
  int n = blockIdx.x * 256 + threadIdx.x;
  if (n >= NN) return;
  int b = off[n], e = off[n + 1];
  float a0 = 0.f, a1 = 0.f, a2 = 0.f;
  int i = b;
  for (; i + 4 <= e; i += 4) {
    int s0 = csr[i], s1 = csr[i + 1], s2 = csr[i + 2], s3 = csr[i + 3];
    float p00 = pos[s0 * 3 + 0], p01 = pos[s0 * 3 + 1], p02 = pos[s0 * 3 + 2];
    float p10 = pos[s1 * 3 + 0], p11 = pos[s1 * 3 + 1], p12 = pos[s1 * 3 + 2];
    float p20 = pos[s2 * 3 + 0], p21 = pos[s2 * 3 + 1], p22 = pos[s2 * 3 + 2];
    float p30 = pos[s3 * 3 + 0], p31 = pos[s3 * 3 + 1], p32 = pos[s3 * 3 + 2];
    a0 += (p00 + p10) + (p20 + p30);
    a1 += (p01 + p11) + (p21 + p31);
    a2 += (p02 + p12) + (p22 + p32);
  }
  for (; i < e; i++) {
    int s = csr[i];
    a0 += pos[s * 3 + 0];
    a1 += pos[s * 3 + 1];
    a2 += pos[s * 3 + 2];
  }
  float rd = 1.0f / fmaxf((float)(e - b), 1.0f);
  agg3[n * 3 + 0] = a0 * rd;
  agg3[n * 3 + 1] = a1 * rd;
  agg3[n * 3 + 2] = a2 * rd;
}

// ---------------- layer-1 node update (3 -> 128), writes fp16 ---------------
__global__ __launch_bounds__(256) void k_node1(
    const float* __restrict__ agg3, const float* __restrict__ pos,
    const float* __restrict__ wl, const float* __restrict__ bl,
    const float* __restrict__ wr, const float* __restrict__ g,
    const float* __restrict__ be, const float* __restrict__ bm,
    const float* __restrict__ bv, f16* __restrict__ x) {
  const int c = threadIdx.x & 127;
  const int np = threadIdx.x >> 7;  // node parity (uniform per wave)
  const float Wl0 = wl[c], Wl1 = wl[CC + c], Wl2 = wl[2 * CC + c];
  const float Wr0 = wr[c], Wr1 = wr[CC + c], Wr2 = wr[2 * CC + c];
  const float sc = g[c] * rsqrtf(bv[c] + 1e-5f);
  const float o0 = be[c] + (bl[c] - bm[c]) * sc;
  const int nbase = blockIdx.x * 256;
  const int nend = min(nbase + 256, NN);
#pragma unroll 4
  for (int n = nbase + np; n < nend; n += 2) {
    float acc = agg3[n * 3 + 0] * Wl0 + agg3[n * 3 + 1] * Wl1 +
                agg3[n * 3 + 2] * Wl2 + pos[n * 3 + 0] * Wr0 +
                pos[n * 3 + 1] * Wr1 + pos[n * 3 + 2] * Wr2;
    x[(size_t)n * CC + c] = (f16)fmaxf(acc * sc + o0, 0.0f);
  }
}

// -------- aggregate (C=128): one wave per node, 16-deep load pipeline -------
// NT on csr loads + agg stores: keep the random-gather rows resident in L2
// (streams must not allocate/evict - R6 lesson in reverse).
__global__ __launch_bounds__(256) void k_aggregate(const int* __restrict__ off,
                                                   const int* __restrict__ csr,
                                                   const f16* __restrict__ x,
                                                   f16* __restrict__ agg) {
  const int n = blockIdx.x * 4 + (threadIdx.x >> 6);
  const int lane = threadIdx.x & 63;
  const int b = off[n], e = off[n + 1];
  float a0 = 0.f, a1 = 0.f;
  int i = b;
  // clean 16-deep blocks
  for (; i + 16 <= e; i += 16) {
    int sdx[16];
#pragma unroll
    for (int q = 0; q < 16; q++) sdx[q] = __builtin_nontemporal_load(csr + i + q);
    f16x2 v[16];
#pragma unroll
    for (int q = 0; q < 16; q++)
      v[q] = *(const f16x2*)(x + (size_t)sdx[q] * CC + lane * 2);
#pragma unroll
    for (int q = 0; q < 16; q++) {
      a0 += (float)v[q][0];
      a1 += (float)v[q][1];
    }
  }
  // one predicated 16-block tail: clamp index (dup loads = same-addr L1 hits)
  const int lim = e - i;
  if (lim > 0) {
    int sdx[16];
#pragma unroll
    for (int q = 0; q < 16; q++)
      sdx[q] = __builtin_nontemporal_load(csr + i + (q < lim ? q : lim - 1));
    f16x2 v[16];
#pragma unroll
    for (int q = 0; q < 16; q++)
      v[q] = *(const f16x2*)(x + (size_t)sdx[q] * CC + lane * 2);
#pragma unroll
    for (int q = 0; q < 16; q++) {
      if (q < lim) {
        a0 += (float)v[q][0];
        a1 += (float)v[q][1];
      }
    }
  }
  const float rd = 1.0f / fmaxf((float)(e - b), 1.0f);
  f16x2 o;
  o[0] = (f16)(a0 * rd);
  o[1] = (f16)(a1 * rd);
  __builtin_nontemporal_store(o, (f16x2*)(agg + (size_t)n * CC + lane * 2));
}

// ---------------- SAGE MFMA fp16: D = agg@wl + x@wr, BN+ReLU ----------------
__global__ __launch_bounds__(256) void k_sage_mfma(
    const f16* __restrict__ xin, f16* __restrict__ xout,
    const f16* __restrict__ agg, const f16* __restrict__ wl,
    const f16* __restrict__ wr, const float* __restrict__ bl,
    const float* __restrict__ g, const float* __restrict__ be,
    const float* __restrict__ bm, const float* __restrict__ bv) {
  const int lane = threadIdx.x & 63;
  const int wave = threadIdx.x >> 6;
  const int c16 = lane & 15;
  const int quad = lane >> 4;
  const int n0 = blockIdx.x * 64 + wave * 16;
  const int rowX = n0 + c16;
  const int rowA = min(rowX, NN - 1);  // agg (in d_out) is not padded
  const f16* px = xin + (size_t)rowX * CC + quad * 8;
  const f16* pa = agg + (size_t)rowA * CC + quad * 8;
  f32x4 acc[8];
#pragma unroll
  for (int t = 0; t < 8; t++) acc[t] = {0.f, 0.f, 0.f, 0.f};
#pragma unroll
  for (int ks = 0; ks < 4; ks++) {
    f16x8 Ax = *(const f16x8*)(px + ks * 32);
    f16x8 Aa = *(const f16x8*)(pa + ks * 32);
#pragma unroll
    for (int nt = 0; nt < 8; nt++) {
      const size_t wo = (size_t)((nt * 4 + ks) * 64 + lane) * 8;
      f16x8 Bl = *(const f16x8*)(wl + wo);
      f16x8 Br = *(const f16x8*)(wr + wo);
      acc[nt] = MFMA16(Aa, Bl, acc[nt]);
      acc[nt] = MFMA16(Ax, Br, acc[nt]);
    }
  }
#pragma unroll
  for (int nt = 0; nt < 8; nt++) {
    const int col = nt * 16 + c16;
    const float blc = bl[col];
    const float sc = g[col] * rsqrtf(bv[col] + 1e-5f);
    const float mm = bm[col];
    const float bb = be[col];
#pragma unroll
    for (int r = 0; r < 4; r++) {
      const int node = n0 + quad * 4 + r;
      if (node < NN) {
        float yv = fmaxf((acc[nt][r] + blc - mm) * sc + bb, 0.0f);
        xout[(size_t)node * CC + col] = (f16)yv;
      }
    }
  }
}

// -------- fused FC head: out = (relu(x@w1+b1)@w2+b2)@w3+b3, LDS relayout ----
__global__ __launch_bounds__(256) void k_dense_fused(
    const f16* __restrict__ x, const f16* __restrict__ w1,
    const f16* __restrict__ w2, const f16* __restrict__ w3,
    const float* __restrict__ b1, const float* __restrict__ b2,
    const float* __restrict__ b3, float* __restrict__ out) {
  const int lane = threadIdx.x & 63;
  const int wave = threadIdx.x >> 6;
  const int c16 = lane & 15;
  const int quad = lane >> 4;
  const int n0 = blockIdx.x * 64 + wave * 16;
  const int lrow = wave * 16;
  __shared__ f16 sh[64][136];  // +8 pad

  f32x4 acc[8];
#pragma unroll
  for (int t = 0; t < 8; t++) acc[t] = {0.f, 0.f, 0.f, 0.f};
  const f16* px = x + (size_t)(n0 + c16) * CC + quad * 8;
#pragma unroll
  for (int ks = 0; ks < 4; ks++) {
    f16x8 Ax = *(const f16x8*)(px + ks * 32);
#pragma unroll
    for (int nt = 0; nt < 8; nt++) {
      f16x8 B = *(const f16x8*)(w1 + (size_t)((nt * 4 + ks) * 64 + lane) * 8);
      acc[nt] = MFMA16(Ax, B, acc[nt]);
    }
  }
#pragma unroll
  for (int nt = 0; nt < 8; nt++) {
    const int col = nt * 16 + c16;
    const float bc = b1[col];
#pragma unroll
    for (int r = 0; r < 4; r++)
      sh[lrow + quad * 4 + r][col] = (f16)fmaxf(acc[nt][r] + bc, 0.0f);
  }
  // FC2 (wave-local rows, no barrier needed)
#pragma unroll
  for (int t = 0; t < 8; t++) acc[t] = {0.f, 0.f, 0.f, 0.f};
#pragma unroll
  for (int ks = 0; ks < 4; ks++) {
    f16x8 Ax = *(const f16x8*)&sh[lrow + c16][ks * 32 + quad * 8];
#pragma unroll
    for (int nt = 0; nt < 8; nt++) {
      f16x8 B = *(const f16x8*)(w2 + (size_t)((nt * 4 + ks) * 64 + lane) * 8);
      acc[nt] = MFMA16(Ax, B, acc[nt]);
    }
  }
#pragma unroll
  for (int nt = 0; nt < 8; nt++) {
    const int col = nt * 16 + c16;
    const float bc = b2[col];
#pragma unroll
    for (int r = 0; r < 4; r++)
      sh[lrow + quad * 4 + r][col] = (f16)(acc[nt][r] + bc);
  }
  // FC3 -> out (fp32)
#pragma unroll
  for (int t = 0; t < 8; t++) acc[t] = {0.f, 0.f, 0.f, 0.f};
#pragma unroll
  for (int ks = 0; ks < 4; ks++) {
    f16x8 Ax = *(const f16x8*)&sh[lrow + c16][ks * 32 + quad * 8];
#pragma unroll
    for (int nt = 0; nt < 8; nt++) {
      f16x8 B = *(const f16x8*)(w3 + (size_t)((nt * 4 + ks) * 64 + lane) * 8);
      acc[nt] = MFMA16(Ax, B, acc[nt]);
    }
  }
#pragma unroll
  for (int nt = 0; nt < 8; nt++) {
    const int col = nt * 16 + c16;
    const float bc = b3[col];
#pragma unroll
    for (int r = 0; r < 4; r++) {
      const int node = n0 + quad * 4 + r;
      if (node < NN) out[(size_t)node * CC + col] = acc[nt][r] + bc;
    }
  }
}

extern "C" void kernel_launch(void* const* d_in, const int* in_sizes, int n_in,
                              void* d_out, int out_size, void* d_ws,
                              size_t ws_size, hipStream_t stream) {
  const float* pos = (const float*)d_in[0];
  const int* ei = (const int*)d_in[1];
  const int* src = ei;
  const int* dst = ei + EE;
  auto P = [&](int i) { return (const float*)d_in[i]; };

  // ws: bcur[NBK] | bbase[NBK] | off[NN+2] | bedge[NBK*BCAP] | csr[E] |
  //     wp16 | xa | xb   (~66 MB)
  int* bcur = (int*)d_ws;
  int* bbase = bcur + NBK;
  int* off = bbase + NBK;
  unsigned* bedge = (unsigned*)(off + NN + 2);
  int* csr = (int*)(bedge + (size_t)NBK * BCAP);
  f16* wp16 = (f16*)(csr + EE);
  f16* xa = wp16 + 9 * 16384;
  f16* xb = xa + (size_t)NP * CC;

  f16* agg = (f16*)d_out;  // scratch until the final dense overwrites d_out

  hipMemsetAsync(bcur, 0, NBK * sizeof(int), stream);

  // CSR build: partition -> bucket scan -> per-bucket offsets+fill
  k_part<<<(EE / 4 + 4095) / 4096, 1024, 0, stream>>>(src, dst, bcur, bedge);
  k_bscan<<<1, 1024, 0, stream>>>(bcur, bbase, off);
  k_bfill2<<<NBK, 256, 0, stream>>>(bcur, bbase, bedge, off, csr);

  WPtrs wp;
  const int wsrc[9] = {9, 11, 16, 18, 23, 25, 30, 32, 34};
  for (int i = 0; i < 9; i++) wp.w[i] = P(wsrc[i]);
  k_packw<<<(9 * 16384) / 256, 256, 0, stream>>>(wp, wp16);

  // layer 1 (Cin=3): agg3 fp32 in d_out scratch (1.2 MB)
  k_agg3<<<(NN + 255) / 256, 256, 0, stream>>>(off, csr, pos, (float*)d_out);
  k_node1<<<(NN + 255) / 256, 256, 0, stream>>>(
      (const float*)d_out, pos, P(2), P(3), P(4), P(5), P(6), P(7), P(8), xa);

  const int NB = NP / 64;  // 1563
  // layers 2..4: ping-pong xa -> xb -> xa -> xb
  const f16* xi = xa;
  f16* xo = xb;
  for (int l = 1; l < 4; l++) {
    int base = 2 + 7 * l;
    int mat = (l - 1) * 2;
    k_aggregate<<<NN / 4, 256, 0, stream>>>(off, csr, xi, agg);
    k_sage_mfma<<<NB, 256, 0, stream>>>(xi, xo, agg,
                                        wp16 + (size_t)mat * 16384,
                                        wp16 + (size_t)(mat + 1) * 16384,
                                        P(base + 1), P(base + 3), P(base + 4),
                                        P(base + 5), P(base + 6));
    const f16* t = xi;
    xi = xo;
    xo = (f16*)t;
  }

  // fused FC head
  k_dense_fused<<<NB, 256, 0, stream>>>(xi, wp16 + (size_t)6 * 16384,
                                        wp16 + (size_t)7 * 16384,
                                        wp16 + (size_t)8 * 16384, P(31), P(33),
                                        P(35), (float*)d_out);
}

// Round 8
// 568.546 us; speedup vs baseline: 2.8012x; 1.0207x over previous
//
#include <hip/hip_runtime.h>

#define NN 100000
#define EE 1600000
#define CC 128
#define NP 100032   // padded to 64-row tiles (1563 * 64)
#define NBK 782     // dst buckets of 128 nodes (782*128 = 100096 >= NN)
#define BCAP 2304   // bucket capacity: E/NBK=2046 expected, +5.6 sigma slack

typedef _Float16 f16;
typedef __attribute__((ext_vector_type(2))) f16 f16x2;
typedef __attribute__((ext_vector_type(8))) f16 f16x8;
typedef __attribute__((ext_vector_type(4))) float f32x4;

#define MFMA16(a, b, c) __builtin_amdgcn_mfma_f32_16x16x32_f16(a, b, c, 0, 0, 0)

// LEDGER (R1-R7): flat [row][128ch] + wave-per-node 16-deep gather is the
// aggregate optimum (76 us, ~3.7 TB/s beyond-L2 wall). Failed challengers:
// 16ch slabs (R2 latency), LDS atomics (R3, 50x), quad/node (R4 divergence),
// degree-sort global atomics (R5), oct+partials (R6 L2 thrash), NT hints +
// sub-histogram CSR build (R7, -0/-15us). This round: fuse aggregate+sage
// into one kernel (kills the 50 MB agg round trip + launch boundary; MFMA
// overlaps gather latency). CSR build reverted to the simple R1 form.

// ---- phase 1: partition edges into dst-buckets; rank saved from 1st pass ----
__global__ __launch_bounds__(1024) void k_part(const int* __restrict__ src,
                                               const int* __restrict__ dst,
                                               int* __restrict__ bcur,
                                               unsigned* __restrict__ bedge) {
  __shared__ int hist[NBK];
  __shared__ int base[NBK];
  const int t = threadIdx.x;
  for (int i = t; i < NBK; i += 1024) hist[i] = 0;
  __syncthreads();
  const int4* src4 = (const int4*)src;
  const int4* dst4 = (const int4*)dst;
  int4 s[4], d[4];
  int rk[16];
  bool val[4];
#pragma unroll
  for (int w = 0; w < 4; w++) {
    int i4 = blockIdx.x * 4096 + w * 1024 + t;
    val[w] = (i4 < EE / 4);
    if (val[w]) {
      s[w] = src4[i4];
      d[w] = dst4[i4];
      rk[w * 4 + 0] = atomicAdd(&hist[d[w].x >> 7], 1);
      rk[w * 4 + 1] = atomicAdd(&hist[d[w].y >> 7], 1);
      rk[w * 4 + 2] = atomicAdd(&hist[d[w].z >> 7], 1);
      rk[w * 4 + 3] = atomicAdd(&hist[d[w].w >> 7], 1);
    }
  }
  __syncthreads();
  for (int i = t; i < NBK; i += 1024) {
    int c = hist[i];
    base[i] = c ? atomicAdd(&bcur[i], c) : 0;
  }
  __syncthreads();
#pragma unroll
  for (int w = 0; w < 4; w++) {
    if (val[w]) {
      int ss[4] = {s[w].x, s[w].y, s[w].z, s[w].w};
      int dd[4] = {d[w].x, d[w].y, d[w].z, d[w].w};
#pragma unroll
      for (int q = 0; q < 4; q++) {
        int b = dd[q] >> 7;
        int slot = base[b] + rk[w * 4 + q];
        if (slot < BCAP)
          bedge[(size_t)b * BCAP + slot] =
              (unsigned)ss[q] | ((unsigned)(dd[q] & 127) << 17);
      }
    }
  }
}

// ---- bucket-count exclusive scan (one block) -> bbase, off[NN] -------------
__global__ __launch_bounds__(1024) void k_bscan(const int* __restrict__ bcur,
                                                int* __restrict__ bbase,
                                                int* __restrict__ off) {
  __shared__ int sh[1024];
  int t = threadIdx.x;
  int v = (t < NBK) ? min(bcur[t], BCAP) : 0;
  sh[t] = v;
  __syncthreads();
  for (int d = 1; d < 1024; d <<= 1) {
    int a = (t >= d) ? sh[t - d] : 0;
    __syncthreads();
    sh[t] += a;
    __syncthreads();
  }
  if (t < NBK) bbase[t] = sh[t] - v;  // exclusive
  if (t == 1023) off[NN] = sh[1023];  // total (== kept edges)
}

// ---- per-bucket: hist -> node offsets (off) -> CSR fill --------------------
__global__ __launch_bounds__(256) void k_bfill2(const int* __restrict__ bcur,
                                                const int* __restrict__ bbase,
                                                const unsigned* __restrict__ bedge,
                                                int* __restrict__ off,
                                                int* __restrict__ csr) {
  __shared__ int h[128];
  __shared__ int sc[128];
  __shared__ int curs[128];
  const int b = blockIdx.x;
  const int t = threadIdx.x;
  if (t < 128) h[t] = 0;
  __syncthreads();
  const int cnt = min(bcur[b], BCAP);
  const unsigned* be = bedge + (size_t)b * BCAP;
  for (int i = t; i < cnt; i += 256) atomicAdd(&h[(be[i] >> 17) & 127], 1);
  __syncthreads();
  int v = (t < 128) ? h[t] : 0;
  if (t < 128) sc[t] = v;
  __syncthreads();
  for (int d = 1; d < 128; d <<= 1) {
    int a = (t >= d && t < 128) ? sc[t - d] : 0;
    __syncthreads();
    if (t < 128) sc[t] += a;
    __syncthreads();
  }
  if (t < 128) {
    int o = bbase[b] + sc[t] - v;  // exclusive node offset
    int n = b * 128 + t;
    if (n < NN) off[n] = o;
    curs[t] = o;
  }
  __syncthreads();
  for (int i = t; i < cnt; i += 256) {
    unsigned u = be[i];
    int node = (u >> 17) & 127;
    int p = atomicAdd(&curs[node], 1);
    csr[p] = (int)(u & 0x1FFFF);
  }
}

// ------- weight pack: fp32 [k][n] -> fp16 in MFMA B-fragment order ----------
struct WPtrs { const float* w[9]; };
__global__ __launch_bounds__(256) void k_packw(WPtrs wp, f16* __restrict__ out) {
  int t = blockIdx.x * 256 + threadIdx.x;  // 9 * 16384
  int mat = t >> 14;
  int idx = t & 16383;
  int j = idx & 7;
  int lane = (idx >> 3) & 63;
  int ks = (idx >> 9) & 3;
  int nt = idx >> 11;
  int c16 = lane & 15, quad = lane >> 4;
  int k = ks * 32 + quad * 8 + j;
  int n = nt * 16 + c16;
  out[(size_t)mat * 16384 + idx] = (f16)wp.w[mat][k * CC + n];
}

// ---------------- layer-1 aggregate (Cin=3), 4-wide neighbor ILP ------------
__global__ __launch_bounds__(256) void k_agg3(const int* __restrict__ off,
                                              const int* __restrict__ csr,
                                              const float* __restrict__ pos,
                                              float* __restrict__ agg3) {
  int n = blockIdx.x * 256 + threadIdx.x;
  if (n >= NN) return;
  int b = off[n], e = off[n + 1];
  float a0 = 0.f, a1 = 0.f, a2 = 0.f;
  int i = b;
  for (; i + 4 <= e; i += 4) {
    int s0 = csr[i], s1 = csr[i + 1], s2 = csr[i + 2], s3 = csr[i + 3];
    float p00 = pos[s0 * 3 + 0], p01 = pos[s0 * 3 + 1], p02 = pos[s0 * 3 + 2];
    float p10 = pos[s1 * 3 + 0], p11 = pos[s1 * 3 + 1], p12 = pos[s1 * 3 + 2];
    float p20 = pos[s2 * 3 + 0], p21 = pos[s2 * 3 + 1], p22 = pos[s2 * 3 + 2];
    float p30 = pos[s3 * 3 + 0], p31 = pos[s3 * 3 + 1], p32 = pos[s3 * 3 + 2];
    a0 += (p00 + p10) + (p20 + p30);
    a1 += (p01 + p11) + (p21 + p31);
    a2 += (p02 + p12) + (p22 + p32);
  }
  for (; i < e; i++) {
    int s = csr[i];
    a0 += pos[s * 3 + 0];
    a1 += pos[s * 3 + 1];
    a2 += pos[s * 3 + 2];
  }
  float rd = 1.0f / fmaxf((float)(e - b), 1.0f);
  agg3[n * 3 + 0] = a0 * rd;
  agg3[n * 3 + 1] = a1 * rd;
  agg3[n * 3 + 2] = a2 * rd;
}

// ---------------- layer-1 node update (3 -> 128), writes fp16 ---------------
__global__ __launch_bounds__(256) void k_node1(
    const float* __restrict__ agg3, const float* __restrict__ pos,
    const float* __restrict__ wl, const float* __restrict__ bl,
    const float* __restrict__ wr, const float* __restrict__ g,
    const float* __restrict__ be, const float* __restrict__ bm,
    const float* __restrict__ bv, f16* __restrict__ x) {
  const int c = threadIdx.x & 127;
  const int np = threadIdx.x >> 7;  // node parity (uniform per wave)
  const float Wl0 = wl[c], Wl1 = wl[CC + c], Wl2 = wl[2 * CC + c];
  const float Wr0 = wr[c], Wr1 = wr[CC + c], Wr2 = wr[2 * CC + c];
  const float sc = g[c] * rsqrtf(bv[c] + 1e-5f);
  const float o0 = be[c] + (bl[c] - bm[c]) * sc;
  const int nbase = blockIdx.x * 256;
  const int nend = min(nbase + 256, NN);
#pragma unroll 4
  for (int n = nbase + np; n < nend; n += 2) {
    float acc = agg3[n * 3 + 0] * Wl0 + agg3[n * 3 + 1] * Wl1 +
                agg3[n * 3 + 2] * Wl2 + pos[n * 3 + 0] * Wr0 +
                pos[n * 3 + 1] * Wr1 + pos[n * 3 + 2] * Wr2;
    x[(size_t)n * CC + c] = (f16)fmaxf(acc * sc + o0, 0.0f);
  }
}

// ---- FUSED aggregate + SAGE MFMA: one block = 64-row tile ------------------
// Phase 1: each of 4 waves aggregates its own 16 nodes (R1's proven 16-deep
// wave-per-node gather), parks f16 means in the LDS tile (dense-kernel [64]
// [136] layout: 2-way-conflict MFMA reads = free). Phase 2: D = agg@wl +
// x@wr with Aa fragments from LDS. Rows are wave-local -> NO barriers; the
// agg global round trip (50 MB/layer) disappears.
__global__ __launch_bounds__(256) void k_agg_sage(
    const int* __restrict__ off, const int* __restrict__ csr,
    const f16* __restrict__ xin, f16* __restrict__ xout,
    const f16* __restrict__ wl, const f16* __restrict__ wr,
    const float* __restrict__ bl, const float* __restrict__ g,
    const float* __restrict__ be, const float* __restrict__ bm,
    const float* __restrict__ bv) {
  const int lane = threadIdx.x & 63;
  const int wave = threadIdx.x >> 6;
  const int c16 = lane & 15;
  const int quad = lane >> 4;
  const int n0 = blockIdx.x * 64 + wave * 16;  // this wave's 16 rows
  const int lrow = wave * 16;
  __shared__ f16 sh[64][136];  // +8 pad (proven pattern from k_dense_fused)

  // ---- phase 1: aggregate 16 nodes, whole wave per node ----
  for (int k = 0; k < 16; k++) {
    const int n = n0 + k;
    float a0 = 0.f, a1 = 0.f;
    if (n < NN) {
      const int b = off[n], e = off[n + 1];
      int i = b;
      for (; i + 16 <= e; i += 16) {
        int sdx[16];
#pragma unroll
        for (int q = 0; q < 16; q++) sdx[q] = csr[i + q];
        f16x2 v[16];
#pragma unroll
        for (int q = 0; q < 16; q++)
          v[q] = *(const f16x2*)(xin + (size_t)sdx[q] * CC + lane * 2);
#pragma unroll
        for (int q = 0; q < 16; q++) {
          a0 += (float)v[q][0];
          a1 += (float)v[q][1];
        }
      }
      const int lim = e - i;
      if (lim > 0) {
        int sdx[16];
#pragma unroll
        for (int q = 0; q < 16; q++) sdx[q] = csr[i + (q < lim ? q : lim - 1)];
        f16x2 v[16];
#pragma unroll
        for (int q = 0; q < 16; q++)
          v[q] = *(const f16x2*)(xin + (size_t)sdx[q] * CC + lane * 2);
#pragma unroll
        for (int q = 0; q < 16; q++) {
          if (q < lim) {
            a0 += (float)v[q][0];
            a1 += (float)v[q][1];
          }
        }
      }
      const float rd = 1.0f / fmaxf((float)(e - b), 1.0f);
      a0 *= rd;
      a1 *= rd;
    }
    f16x2 o;
    o[0] = (f16)a0;
    o[1] = (f16)a1;  // same f16 rounding point as the old global agg store
    *(f16x2*)&sh[lrow + k][lane * 2] = o;  // 64 lanes -> 256 B consecutive
  }

  // ---- phase 2: MFMA epilogue (wave-local rows; no __syncthreads) ----
  const int rowX = n0 + c16;
  const f16* px = xin + (size_t)rowX * CC + quad * 8;
  f32x4 acc[8];
#pragma unroll
  for (int t = 0; t < 8; t++) acc[t] = {0.f, 0.f, 0.f, 0.f};
#pragma unroll
  for (int ks = 0; ks < 4; ks++) {
    f16x8 Ax = *(const f16x8*)(px + ks * 32);
    f16x8 Aa = *(const f16x8*)&sh[lrow + c16][ks * 32 + quad * 8];
#pragma unroll
    for (int nt = 0; nt < 8; nt++) {
      const size_t wo = (size_t)((nt * 4 + ks) * 64 + lane) * 8;
      f16x8 Bl = *(const f16x8*)(wl + wo);
      f16x8 Br = *(const f16x8*)(wr + wo);
      acc[nt] = MFMA16(Aa, Bl, acc[nt]);
      acc[nt] = MFMA16(Ax, Br, acc[nt]);
    }
  }
#pragma unroll
  for (int nt = 0; nt < 8; nt++) {
    const int col = nt * 16 + c16;
    const float blc = bl[col];
    const float sc = g[col] * rsqrtf(bv[col] + 1e-5f);
    const float mm = bm[col];
    const float bb = be[col];
#pragma unroll
    for (int r = 0; r < 4; r++) {
      const int node = n0 + quad * 4 + r;
      if (node < NN) {
        float yv = fmaxf((acc[nt][r] + blc - mm) * sc + bb, 0.0f);
        xout[(size_t)node * CC + col] = (f16)yv;
      }
    }
  }
}

// -------- fused FC head: out = (relu(x@w1+b1)@w2+b2)@w3+b3, LDS relayout ----
__global__ __launch_bounds__(256) void k_dense_fused(
    const f16* __restrict__ x, const f16* __restrict__ w1,
    const f16* __restrict__ w2, const f16* __restrict__ w3,
    const float* __restrict__ b1, const float* __restrict__ b2,
    const float* __restrict__ b3, float* __restrict__ out) {
  const int lane = threadIdx.x & 63;
  const int wave = threadIdx.x >> 6;
  const int c16 = lane & 15;
  const int quad = lane >> 4;
  const int n0 = blockIdx.x * 64 + wave * 16;
  const int lrow = wave * 16;
  __shared__ f16 sh[64][136];  // +8 pad

  f32x4 acc[8];
#pragma unroll
  for (int t = 0; t < 8; t++) acc[t] = {0.f, 0.f, 0.f, 0.f};
  const f16* px = x + (size_t)(n0 + c16) * CC + quad * 8;
#pragma unroll
  for (int ks = 0; ks < 4; ks++) {
    f16x8 Ax = *(const f16x8*)(px + ks * 32);
#pragma unroll
    for (int nt = 0; nt < 8; nt++) {
      f16x8 B = *(const f16x8*)(w1 + (size_t)((nt * 4 + ks) * 64 + lane) * 8);
      acc[nt] = MFMA16(Ax, B, acc[nt]);
    }
  }
#pragma unroll
  for (int nt = 0; nt < 8; nt++) {
    const int col = nt * 16 + c16;
    const float bc = b1[col];
#pragma unroll
    for (int r = 0; r < 4; r++)
      sh[lrow + quad * 4 + r][col] = (f16)fmaxf(acc[nt][r] + bc, 0.0f);
  }
  // FC2 (wave-local rows, no barrier needed)
#pragma unroll
  for (int t = 0; t < 8; t++) acc[t] = {0.f, 0.f, 0.f, 0.f};
#pragma unroll
  for (int ks = 0; ks < 4; ks++) {
    f16x8 Ax = *(const f16x8*)&sh[lrow + c16][ks * 32 + quad * 8];
#pragma unroll
    for (int nt = 0; nt < 8; nt++) {
      f16x8 B = *(const f16x8*)(w2 + (size_t)((nt * 4 + ks) * 64 + lane) * 8);
      acc[nt] = MFMA16(Ax, B, acc[nt]);
    }
  }
#pragma unroll
  for (int nt = 0; nt < 8; nt++) {
    const int col = nt * 16 + c16;
    const float bc = b2[col];
#pragma unroll
    for (int r = 0; r < 4; r++)
      sh[lrow + quad * 4 + r][col] = (f16)(acc[nt][r] + bc);
  }
  // FC3 -> out (fp32)
#pragma unroll
  for (int t = 0; t < 8; t++) acc[t] = {0.f, 0.f, 0.f, 0.f};
#pragma unroll
  for (int ks = 0; ks < 4; ks++) {
    f16x8 Ax = *(const f16x8*)&sh[lrow + c16][ks * 32 + quad * 8];
#pragma unroll
    for (int nt = 0; nt < 8; nt++) {
      f16x8 B = *(const f16x8*)(w3 + (size_t)((nt * 4 + ks) * 64 + lane) * 8);
      acc[nt] = MFMA16(Ax, B, acc[nt]);
    }
  }
#pragma unroll
  for (int nt = 0; nt < 8; nt++) {
    const int col = nt * 16 + c16;
    const float bc = b3[col];
#pragma unroll
    for (int r = 0; r < 4; r++) {
      const int node = n0 + quad * 4 + r;
      if (node < NN) out[(size_t)node * CC + col] = acc[nt][r] + bc;
    }
  }
}

extern "C" void kernel_launch(void* const* d_in, const int* in_sizes, int n_in,
                              void* d_out, int out_size, void* d_ws,
                              size_t ws_size, hipStream_t stream) {
  const float* pos = (const float*)d_in[0];
  const int* ei = (const int*)d_in[1];
  const int* src = ei;
  const int* dst = ei + EE;
  auto P = [&](int i) { return (const float*)d_in[i]; };

  // ws: bcur[NBK] | bbase[NBK] | off[NN+2] | bedge[NBK*BCAP] | csr[E] |
  //     wp16 | xa | xb   (~66 MB)
  int* bcur = (int*)d_ws;
  int* bbase = bcur + NBK;
  int* off = bbase + NBK;
  unsigned* bedge = (unsigned*)(off + NN + 2);
  int* csr = (int*)(bedge + (size_t)NBK * BCAP);
  f16* wp16 = (f16*)(csr + EE);
  f16* xa = wp16 + 9 * 16384;
  f16* xb = xa + (size_t)NP * CC;

  hipMemsetAsync(bcur, 0, NBK * sizeof(int), stream);

  // CSR build: partition -> bucket scan -> per-bucket offsets+fill
  k_part<<<(EE / 4 + 4095) / 4096, 1024, 0, stream>>>(src, dst, bcur, bedge);
  k_bscan<<<1, 1024, 0, stream>>>(bcur, bbase, off);
  k_bfill2<<<NBK, 256, 0, stream>>>(bcur, bbase, bedge, off, csr);

  WPtrs wp;
  const int wsrc[9] = {9, 11, 16, 18, 23, 25, 30, 32, 34};
  for (int i = 0; i < 9; i++) wp.w[i] = P(wsrc[i]);
  k_packw<<<(9 * 16384) / 256, 256, 0, stream>>>(wp, wp16);

  // layer 1 (Cin=3): agg3 fp32 in d_out scratch (1.2 MB)
  k_agg3<<<(NN + 255) / 256, 256, 0, stream>>>(off, csr, pos, (float*)d_out);
  k_node1<<<(NN + 255) / 256, 256, 0, stream>>>(
      (const float*)d_out, pos, P(2), P(3), P(4), P(5), P(6), P(7), P(8), xa);

  const int NB = NP / 64;  // 1563
  // layers 2..4 (fused aggregate+sage): ping-pong xa -> xb -> xa -> xb
  const f16* xi = xa;
  f16* xo = xb;
  for (int l = 1; l < 4; l++) {
    int base = 2 + 7 * l;
    int mat = (l - 1) * 2;
    k_agg_sage<<<NB, 256, 0, stream>>>(off, csr, xi, xo,
                                       wp16 + (size_t)mat * 16384,
                                       wp16 + (size_t)(mat + 1) * 16384,
                                       P(base + 1), P(base + 3), P(base + 4),
                                       P(base + 5), P(base + 6));
    const f16* t = xi;
    xi = xo;
    xo = (f16*)t;
  }

  // fused FC head
  k_dense_fused<<<NB, 256, 0, stream>>>(xi, wp16 + (size_t)6 * 16384,
                                        wp16 + (size_t)7 * 16384,
                                        wp16 + (size_t)8 * 16384, P(31), P(33),
                                        P(35), (float*)d_out);
}

// Round 9
// 562.297 us; speedup vs baseline: 2.8323x; 1.0111x over previous
//
#include <hip/hip_runtime.h>

#define NN 100000
#define EE 1600000
#define CC 128
#define NP 100032   // padded to 64-row tiles (1563 * 64)
#define NBK 782     // dst buckets of 128 nodes (782*128 = 100096 >= NN)
#define BCAP 2304   // bucket capacity: E/NBK=2046 expected, +5.6 sigma slack

typedef _Float16 f16;
typedef __attribute__((ext_vector_type(2))) f16 f16x2;
typedef __attribute__((ext_vector_type(8))) f16 f16x8;
typedef __attribute__((ext_vector_type(4))) float f32x4;

#define MFMA16(a, b, c) __builtin_amdgcn_mfma_f32_16x16x32_f16(a, b, c, 0, 0, 0)

// LEDGER (R1-R8): flat [row][128ch] + wave-per-node 16-deep gather is the
// aggregate optimum (76 us). Wall arithmetic: FETCH 257MB/76us = 3.4 TB/s =
// ~2.7 line-misses/cyc/XCD (L2 miss-handling rate). Failed challengers:
// 16ch slabs (R2 wave-latency), LDS atomics (R3 50x), quad/node (R4 TA
// line-throughput: 64 lines/instr vs 4 for full-row), degree-sort w/ global
// atomics (R5), oct+partials (R6 depth-1 + write thrash), NT hints (R7 no-op),
// sub-histogram CSR (R7 -15us), agg+sage fusion (R8 occupancy 70->33%).
// This round: R1 pipeline + agg3/node1 fused via LDS (k_layer1).

// ---- phase 1: partition edges into dst-buckets; rank saved from 1st pass ----
__global__ __launch_bounds__(1024) void k_part(const int* __restrict__ src,
                                               const int* __restrict__ dst,
                                               int* __restrict__ bcur,
                                               unsigned* __restrict__ bedge) {
  __shared__ int hist[NBK];
  __shared__ int base[NBK];
  const int t = threadIdx.x;
  for (int i = t; i < NBK; i += 1024) hist[i] = 0;
  __syncthreads();
  const int4* src4 = (const int4*)src;
  const int4* dst4 = (const int4*)dst;
  int4 s[4], d[4];
  int rk[16];
  bool val[4];
#pragma unroll
  for (int w = 0; w < 4; w++) {
    int i4 = blockIdx.x * 4096 + w * 1024 + t;
    val[w] = (i4 < EE / 4);
    if (val[w]) {
      s[w] = src4[i4];
      d[w] = dst4[i4];
      rk[w * 4 + 0] = atomicAdd(&hist[d[w].x >> 7], 1);
      rk[w * 4 + 1] = atomicAdd(&hist[d[w].y >> 7], 1);
      rk[w * 4 + 2] = atomicAdd(&hist[d[w].z >> 7], 1);
      rk[w * 4 + 3] = atomicAdd(&hist[d[w].w >> 7], 1);
    }
  }
  __syncthreads();
  for (int i = t; i < NBK; i += 1024) {
    int c = hist[i];
    base[i] = c ? atomicAdd(&bcur[i], c) : 0;
  }
  __syncthreads();
#pragma unroll
  for (int w = 0; w < 4; w++) {
    if (val[w]) {
      int ss[4] = {s[w].x, s[w].y, s[w].z, s[w].w};
      int dd[4] = {d[w].x, d[w].y, d[w].z, d[w].w};
#pragma unroll
      for (int q = 0; q < 4; q++) {
        int b = dd[q] >> 7;
        int slot = base[b] + rk[w * 4 + q];
        if (slot < BCAP)
          bedge[(size_t)b * BCAP + slot] =
              (unsigned)ss[q] | ((unsigned)(dd[q] & 127) << 17);
      }
    }
  }
}

// ---- bucket-count exclusive scan (one block) -> bbase, off[NN] -------------
__global__ __launch_bounds__(1024) void k_bscan(const int* __restrict__ bcur,
                                                int* __restrict__ bbase,
                                                int* __restrict__ off) {
  __shared__ int sh[1024];
  int t = threadIdx.x;
  int v = (t < NBK) ? min(bcur[t], BCAP) : 0;
  sh[t] = v;
  __syncthreads();
  for (int d = 1; d < 1024; d <<= 1) {
    int a = (t >= d) ? sh[t - d] : 0;
    __syncthreads();
    sh[t] += a;
    __syncthreads();
  }
  if (t < NBK) bbase[t] = sh[t] - v;  // exclusive
  if (t == 1023) off[NN] = sh[1023];  // total (== kept edges)
}

// ---- per-bucket: hist -> node offsets (off) -> CSR fill --------------------
__global__ __launch_bounds__(256) void k_bfill2(const int* __restrict__ bcur,
                                                const int* __restrict__ bbase,
                                                const unsigned* __restrict__ bedge,
                                                int* __restrict__ off,
                                                int* __restrict__ csr) {
  __shared__ int h[128];
  __shared__ int sc[128];
  __shared__ int curs[128];
  const int b = blockIdx.x;
  const int t = threadIdx.x;
  if (t < 128) h[t] = 0;
  __syncthreads();
  const int cnt = min(bcur[b], BCAP);
  const unsigned* be = bedge + (size_t)b * BCAP;
  for (int i = t; i < cnt; i += 256) atomicAdd(&h[(be[i] >> 17) & 127], 1);
  __syncthreads();
  int v = (t < 128) ? h[t] : 0;
  if (t < 128) sc[t] = v;
  __syncthreads();
  for (int d = 1; d < 128; d <<= 1) {
    int a = (t >= d && t < 128) ? sc[t - d] : 0;
    __syncthreads();
    if (t < 128) sc[t] += a;
    __syncthreads();
  }
  if (t < 128) {
    int o = bbase[b] + sc[t] - v;  // exclusive node offset
    int n = b * 128 + t;
    if (n < NN) off[n] = o;
    curs[t] = o;
  }
  __syncthreads();
  for (int i = t; i < cnt; i += 256) {
    unsigned u = be[i];
    int node = (u >> 17) & 127;
    int p = atomicAdd(&curs[node], 1);
    csr[p] = (int)(u & 0x1FFFF);
  }
}

// ------- weight pack: fp32 [k][n] -> fp16 in MFMA B-fragment order ----------
struct WPtrs { const float* w[9]; };
__global__ __launch_bounds__(256) void k_packw(WPtrs wp, f16* __restrict__ out) {
  int t = blockIdx.x * 256 + threadIdx.x;  // 9 * 16384
  int mat = t >> 14;
  int idx = t & 16383;
  int j = idx & 7;
  int lane = (idx >> 3) & 63;
  int ks = (idx >> 9) & 3;
  int nt = idx >> 11;
  int c16 = lane & 15, quad = lane >> 4;
  int k = ks * 32 + quad * 8 + j;
  int n = nt * 16 + c16;
  out[(size_t)mat * 16384 + idx] = (f16)wp.w[mat][k * CC + n];
}

// ---- FUSED layer 1: agg3 (thread-per-node, LDS) + node update (3 -> 128) ---
// Phase A: each thread aggregates pos over its node's neighbors -> sa[256][3].
// Phase B: node1's channel-parallel update reads sa via LDS broadcast.
// Kills the 2.4 MB agg3 round trip + one dispatch. Numerics identical.
__global__ __launch_bounds__(256) void k_layer1(
    const int* __restrict__ off, const int* __restrict__ csr,
    const float* __restrict__ pos, const float* __restrict__ wl,
    const float* __restrict__ bl, const float* __restrict__ wr,
    const float* __restrict__ g, const float* __restrict__ be,
    const float* __restrict__ bm, const float* __restrict__ bv,
    f16* __restrict__ x) {
  __shared__ float sa[256][3];
  const int t = threadIdx.x;
  const int nbase = blockIdx.x * 256;
  {
    const int n = nbase + t;
    float a0 = 0.f, a1 = 0.f, a2 = 0.f;
    if (n < NN) {
      const int b = off[n], e = off[n + 1];
      int i = b;
      for (; i + 4 <= e; i += 4) {
        int s0 = csr[i], s1 = csr[i + 1], s2 = csr[i + 2], s3 = csr[i + 3];
        float p00 = pos[s0 * 3 + 0], p01 = pos[s0 * 3 + 1], p02 = pos[s0 * 3 + 2];
        float p10 = pos[s1 * 3 + 0], p11 = pos[s1 * 3 + 1], p12 = pos[s1 * 3 + 2];
        float p20 = pos[s2 * 3 + 0], p21 = pos[s2 * 3 + 1], p22 = pos[s2 * 3 + 2];
        float p30 = pos[s3 * 3 + 0], p31 = pos[s3 * 3 + 1], p32 = pos[s3 * 3 + 2];
        a0 += (p00 + p10) + (p20 + p30);
        a1 += (p01 + p11) + (p21 + p31);
        a2 += (p02 + p12) + (p22 + p32);
      }
      for (; i < e; i++) {
        int s = csr[i];
        a0 += pos[s * 3 + 0];
        a1 += pos[s * 3 + 1];
        a2 += pos[s * 3 + 2];
      }
      const float rd = 1.0f / fmaxf((float)(e - b), 1.0f);
      a0 *= rd;
      a1 *= rd;
      a2 *= rd;
    }
    sa[t][0] = a0;
    sa[t][1] = a1;
    sa[t][2] = a2;
  }
  __syncthreads();
  const int c = t & 127;
  const int np = t >> 7;  // node parity (uniform per wave)
  const float Wl0 = wl[c], Wl1 = wl[CC + c], Wl2 = wl[2 * CC + c];
  const float Wr0 = wr[c], Wr1 = wr[CC + c], Wr2 = wr[2 * CC + c];
  const float sc = g[c] * rsqrtf(bv[c] + 1e-5f);
  const float o0 = be[c] + (bl[c] - bm[c]) * sc;
  const int nend = min(nbase + 256, NN);
#pragma unroll 4
  for (int n = nbase + np; n < nend; n += 2) {
    const int ln = n - nbase;
    float acc = sa[ln][0] * Wl0 + sa[ln][1] * Wl1 + sa[ln][2] * Wl2 +
                pos[n * 3 + 0] * Wr0 + pos[n * 3 + 1] * Wr1 +
                pos[n * 3 + 2] * Wr2;
    x[(size_t)n * CC + c] = (f16)fmaxf(acc * sc + o0, 0.0f);
  }
}

// -------- aggregate (C=128): one wave per node, 16-deep load pipeline -------
__global__ __launch_bounds__(256) void k_aggregate(const int* __restrict__ off,
                                                   const int* __restrict__ csr,
                                                   const f16* __restrict__ x,
                                                   f16* __restrict__ agg) {
  const int n = blockIdx.x * 4 + (threadIdx.x >> 6);
  const int lane = threadIdx.x & 63;
  const int b = off[n], e = off[n + 1];
  float a0 = 0.f, a1 = 0.f;
  int i = b;
  // clean 16-deep blocks
  for (; i + 16 <= e; i += 16) {
    int sdx[16];
#pragma unroll
    for (int q = 0; q < 16; q++) sdx[q] = csr[i + q];
    f16x2 v[16];
#pragma unroll
    for (int q = 0; q < 16; q++)
      v[q] = *(const f16x2*)(x + (size_t)sdx[q] * CC + lane * 2);
#pragma unroll
    for (int q = 0; q < 16; q++) {
      a0 += (float)v[q][0];
      a1 += (float)v[q][1];
    }
  }
  // one predicated 16-block tail: clamp index (dup loads = same-addr L1 hits)
  const int lim = e - i;
  if (lim > 0) {
    int sdx[16];
#pragma unroll
    for (int q = 0; q < 16; q++) sdx[q] = csr[i + (q < lim ? q : lim - 1)];
    f16x2 v[16];
#pragma unroll
    for (int q = 0; q < 16; q++)
      v[q] = *(const f16x2*)(x + (size_t)sdx[q] * CC + lane * 2);
#pragma unroll
    for (int q = 0; q < 16; q++) {
      if (q < lim) {
        a0 += (float)v[q][0];
        a1 += (float)v[q][1];
      }
    }
  }
  const float rd = 1.0f / fmaxf((float)(e - b), 1.0f);
  f16x2 o;
  o[0] = (f16)(a0 * rd);
  o[1] = (f16)(a1 * rd);
  *(f16x2*)(agg + (size_t)n * CC + lane * 2) = o;
}

// ---------------- SAGE MFMA fp16: D = agg@wl + x@wr, BN+ReLU ----------------
__global__ __launch_bounds__(256) void k_sage_mfma(
    const f16* __restrict__ xin, f16* __restrict__ xout,
    const f16* __restrict__ agg, const f16* __restrict__ wl,
    const f16* __restrict__ wr, const float* __restrict__ bl,
    const float* __restrict__ g, const float* __restrict__ be,
    const float* __restrict__ bm, const float* __restrict__ bv) {
  const int lane = threadIdx.x & 63;
  const int wave = threadIdx.x >> 6;
  const int c16 = lane & 15;
  const int quad = lane >> 4;
  const int n0 = blockIdx.x * 64 + wave * 16;
  const int rowX = n0 + c16;
  const int rowA = min(rowX, NN - 1);  // agg (in d_out) is not padded
  const f16* px = xin + (size_t)rowX * CC + quad * 8;
  const f16* pa = agg + (size_t)rowA * CC + quad * 8;
  f32x4 acc[8];
#pragma unroll
  for (int t = 0; t < 8; t++) acc[t] = {0.f, 0.f, 0.f, 0.f};
#pragma unroll
  for (int ks = 0; ks < 4; ks++) {
    f16x8 Ax = *(const f16x8*)(px + ks * 32);
    f16x8 Aa = *(const f16x8*)(pa + ks * 32);
#pragma unroll
    for (int nt = 0; nt < 8; nt++) {
      const size_t wo = (size_t)((nt * 4 + ks) * 64 + lane) * 8;
      f16x8 Bl = *(const f16x8*)(wl + wo);
      f16x8 Br = *(const f16x8*)(wr + wo);
      acc[nt] = MFMA16(Aa, Bl, acc[nt]);
      acc[nt] = MFMA16(Ax, Br, acc[nt]);
    }
  }
#pragma unroll
  for (int nt = 0; nt < 8; nt++) {
    const int col = nt * 16 + c16;
    const float blc = bl[col];
    const float sc = g[col] * rsqrtf(bv[col] + 1e-5f);
    const float mm = bm[col];
    const float bb = be[col];
#pragma unroll
    for (int r = 0; r < 4; r++) {
      const int node = n0 + quad * 4 + r;
      if (node < NN) {
        float yv = fmaxf((acc[nt][r] + blc - mm) * sc + bb, 0.0f);
        xout[(size_t)node * CC + col] = (f16)yv;
      }
    }
  }
}

// -------- fused FC head: out = (relu(x@w1+b1)@w2+b2)@w3+b3, LDS relayout ----
__global__ __launch_bounds__(256) void k_dense_fused(
    const f16* __restrict__ x, const f16* __restrict__ w1,
    const f16* __restrict__ w2, const f16* __restrict__ w3,
    const float* __restrict__ b1, const float* __restrict__ b2,
    const float* __restrict__ b3, float* __restrict__ out) {
  const int lane = threadIdx.x & 63;
  const int wave = threadIdx.x >> 6;
  const int c16 = lane & 15;
  const int quad = lane >> 4;
  const int n0 = blockIdx.x * 64 + wave * 16;
  const int lrow = wave * 16;
  __shared__ f16 sh[64][136];  // +8 pad

  f32x4 acc[8];
#pragma unroll
  for (int t = 0; t < 8; t++) acc[t] = {0.f, 0.f, 0.f, 0.f};
  const f16* px = x + (size_t)(n0 + c16) * CC + quad * 8;
#pragma unroll
  for (int ks = 0; ks < 4; ks++) {
    f16x8 Ax = *(const f16x8*)(px + ks * 32);
#pragma unroll
    for (int nt = 0; nt < 8; nt++) {
      f16x8 B = *(const f16x8*)(w1 + (size_t)((nt * 4 + ks) * 64 + lane) * 8);
      acc[nt] = MFMA16(Ax, B, acc[nt]);
    }
  }
#pragma unroll
  for (int nt = 0; nt < 8; nt++) {
    const int col = nt * 16 + c16;
    const float bc = b1[col];
#pragma unroll
    for (int r = 0; r < 4; r++)
      sh[lrow + quad * 4 + r][col] = (f16)fmaxf(acc[nt][r] + bc, 0.0f);
  }
  // FC2 (wave-local rows, no barrier needed)
#pragma unroll
  for (int t = 0; t < 8; t++) acc[t] = {0.f, 0.f, 0.f, 0.f};
#pragma unroll
  for (int ks = 0; ks < 4; ks++) {
    f16x8 Ax = *(const f16x8*)&sh[lrow + c16][ks * 32 + quad * 8];
#pragma unroll
    for (int nt = 0; nt < 8; nt++) {
      f16x8 B = *(const f16x8*)(w2 + (size_t)((nt * 4 + ks) * 64 + lane) * 8);
      acc[nt] = MFMA16(Ax, B, acc[nt]);
    }
  }
#pragma unroll
  for (int nt = 0; nt < 8; nt++) {
    const int col = nt * 16 + c16;
    const float bc = b2[col];
#pragma unroll
    for (int r = 0; r < 4; r++)
      sh[lrow + quad * 4 + r][col] = (f16)(acc[nt][r] + bc);
  }
  // FC3 -> out (fp32)
#pragma unroll
  for (int t = 0; t < 8; t++) acc[t] = {0.f, 0.f, 0.f, 0.f};
#pragma unroll
  for (int ks = 0; ks < 4; ks++) {
    f16x8 Ax = *(const f16x8*)&sh[lrow + c16][ks * 32 + quad * 8];
#pragma unroll
    for (int nt = 0; nt < 8; nt++) {
      f16x8 B = *(const f16x8*)(w3 + (size_t)((nt * 4 + ks) * 64 + lane) * 8);
      acc[nt] = MFMA16(Ax, B, acc[nt]);
    }
  }
#pragma unroll
  for (int nt = 0; nt < 8; nt++) {
    const int col = nt * 16 + c16;
    const float bc = b3[col];
#pragma unroll
    for (int r = 0; r < 4; r++) {
      const int node = n0 + quad * 4 + r;
      if (node < NN) out[(size_t)node * CC + col] = acc[nt][r] + bc;
    }
  }
}

extern "C" void kernel_launch(void* const* d_in, const int* in_sizes, int n_in,
                              void* d_out, int out_size, void* d_ws,
                              size_t ws_size, hipStream_t stream) {
  const float* pos = (const float*)d_in[0];
  const int* ei = (const int*)d_in[1];
  const int* src = ei;
  const int* dst = ei + EE;
  auto P = [&](int i) { return (const float*)d_in[i]; };

  // ws: bcur[NBK] | bbase[NBK] | off[NN+2] | bedge[NBK*BCAP] | csr[E] |
  //     wp16 | xa | xb   (~66 MB)
  int* bcur = (int*)d_ws;
  int* bbase = bcur + NBK;
  int* off = bbase + NBK;
  unsigned* bedge = (unsigned*)(off + NN + 2);
  int* csr = (int*)(bedge + (size_t)NBK * BCAP);
  f16* wp16 = (f16*)(csr + EE);
  f16* xa = wp16 + 9 * 16384;
  f16* xb = xa + (size_t)NP * CC;

  f16* agg = (f16*)d_out;  // scratch until the final dense overwrites d_out

  hipMemsetAsync(bcur, 0, NBK * sizeof(int), stream);

  // CSR build: partition -> bucket scan -> per-bucket offsets+fill
  k_part<<<(EE / 4 + 4095) / 4096, 1024, 0, stream>>>(src, dst, bcur, bedge);
  k_bscan<<<1, 1024, 0, stream>>>(bcur, bbase, off);
  k_bfill2<<<NBK, 256, 0, stream>>>(bcur, bbase, bedge, off, csr);

  WPtrs wp;
  const int wsrc[9] = {9, 11, 16, 18, 23, 25, 30, 32, 34};
  for (int i = 0; i < 9; i++) wp.w[i] = P(wsrc[i]);
  k_packw<<<(9 * 16384) / 256, 256, 0, stream>>>(wp, wp16);

  // layer 1 (Cin=3), fused aggregate + node update
  k_layer1<<<(NN + 255) / 256, 256, 0, stream>>>(
      off, csr, pos, P(2), P(3), P(4), P(5), P(6), P(7), P(8), xa);

  const int NB = NP / 64;  // 1563
  // layers 2..4: ping-pong xa -> xb -> xa -> xb
  const f16* xi = xa;
  f16* xo = xb;
  for (int l = 1; l < 4; l++) {
    int base = 2 + 7 * l;
    int mat = (l - 1) * 2;
    k_aggregate<<<NN / 4, 256, 0, stream>>>(off, csr, xi, agg);
    k_sage_mfma<<<NB, 256, 0, stream>>>(xi, xo, agg,
                                        wp16 + (size_t)mat * 16384,
                                        wp16 + (size_t)(mat + 1) * 16384,
                                        P(base + 1), P(base + 3), P(base + 4),
                                        P(base + 5), P(base + 6));
    const f16* t = xi;
    xi = xo;
    xo = (f16*)t;
  }

  // fused FC head
  k_dense_fused<<<NB, 256, 0, stream>>>(xi, wp16 + (size_t)6 * 16384,
                                        wp16 + (size_t)7 * 16384,
                                        wp16 + (size_t)8 * 16384, P(31), P(33),
                                        P(35), (float*)d_out);
}

// Round 10
// 516.471 us; speedup vs baseline: 3.0836x; 1.0887x over previous
//
#include <hip/hip_runtime.h>

#define NN 100000
#define EE 1600000
#define CC 128
#define NP 100032   // padded to 64-row tiles (1563 * 64)
#define NBK 782     // dst buckets of 128 nodes (782*128 = 100096 >= NN)
#define BCAP 2304   // bucket capacity: E/NBK=2046 expected, +5.6 sigma slack
#define NBS 782     // 128-row MFMA tiles (782*128 = 100096 >= NP)

typedef _Float16 f16;
typedef __attribute__((ext_vector_type(2))) f16 f16x2;
typedef __attribute__((ext_vector_type(8))) f16 f16x8;
typedef __attribute__((ext_vector_type(4))) float f32x4;

#define MFMA16(a, b, c) __builtin_amdgcn_mfma_f32_16x16x32_f16(a, b, c, 0, 0, 0)

// LEDGER (R1-R9): flat [row][128ch] + wave-per-node 16-deep gather is the
// aggregate optimum (75.6 us, FETCH 257 MB stable; ~3.4 TB/s L2-miss-path
// wall). Failed challengers: 16ch slabs (R2 wave-latency), LDS atomics (R3
// 50x), quad/node (R4 TA line-throughput), degree-sort global atomics (R5),
// oct+partials (R6 depth-1 + write thrash), NT hints (R7 no-op), sub-hist
// CSR (R7 -15us), agg+sage fusion (R8 occupancy 70->33%). R9 best: 562 us.
// This round: pos4 prepack for layer1 + 128-row/512-thread sage & dense
// blocks (halve weight-fragment L2 traffic + launch tail).

// ---- phase 1: partition edges into dst-buckets; rank saved from 1st pass ----
__global__ __launch_bounds__(1024) void k_part(const int* __restrict__ src,
                                               const int* __restrict__ dst,
                                               int* __restrict__ bcur,
                                               unsigned* __restrict__ bedge) {
  __shared__ int hist[NBK];
  __shared__ int base[NBK];
  const int t = threadIdx.x;
  for (int i = t; i < NBK; i += 1024) hist[i] = 0;
  __syncthreads();
  const int4* src4 = (const int4*)src;
  const int4* dst4 = (const int4*)dst;
  int4 s[4], d[4];
  int rk[16];
  bool val[4];
#pragma unroll
  for (int w = 0; w < 4; w++) {
    int i4 = blockIdx.x * 4096 + w * 1024 + t;
    val[w] = (i4 < EE / 4);
    if (val[w]) {
      s[w] = src4[i4];
      d[w] = dst4[i4];
      rk[w * 4 + 0] = atomicAdd(&hist[d[w].x >> 7], 1);
      rk[w * 4 + 1] = atomicAdd(&hist[d[w].y >> 7], 1);
      rk[w * 4 + 2] = atomicAdd(&hist[d[w].z >> 7], 1);
      rk[w * 4 + 3] = atomicAdd(&hist[d[w].w >> 7], 1);
    }
  }
  __syncthreads();
  for (int i = t; i < NBK; i += 1024) {
    int c = hist[i];
    base[i] = c ? atomicAdd(&bcur[i], c) : 0;
  }
  __syncthreads();
#pragma unroll
  for (int w = 0; w < 4; w++) {
    if (val[w]) {
      int ss[4] = {s[w].x, s[w].y, s[w].z, s[w].w};
      int dd[4] = {d[w].x, d[w].y, d[w].z, d[w].w};
#pragma unroll
      for (int q = 0; q < 4; q++) {
        int b = dd[q] >> 7;
        int slot = base[b] + rk[w * 4 + q];
        if (slot < BCAP)
          bedge[(size_t)b * BCAP + slot] =
              (unsigned)ss[q] | ((unsigned)(dd[q] & 127) << 17);
      }
    }
  }
}

// ---- bucket-count exclusive scan (one block) -> bbase, off[NN] -------------
__global__ __launch_bounds__(1024) void k_bscan(const int* __restrict__ bcur,
                                                int* __restrict__ bbase,
                                                int* __restrict__ off) {
  __shared__ int sh[1024];
  int t = threadIdx.x;
  int v = (t < NBK) ? min(bcur[t], BCAP) : 0;
  sh[t] = v;
  __syncthreads();
  for (int d = 1; d < 1024; d <<= 1) {
    int a = (t >= d) ? sh[t - d] : 0;
    __syncthreads();
    sh[t] += a;
    __syncthreads();
  }
  if (t < NBK) bbase[t] = sh[t] - v;  // exclusive
  if (t == 1023) off[NN] = sh[1023];  // total (== kept edges)
}

// ---- per-bucket: hist -> node offsets (off) -> CSR fill --------------------
__global__ __launch_bounds__(256) void k_bfill2(const int* __restrict__ bcur,
                                                const int* __restrict__ bbase,
                                                const unsigned* __restrict__ bedge,
                                                int* __restrict__ off,
                                                int* __restrict__ csr) {
  __shared__ int h[128];
  __shared__ int sc[128];
  __shared__ int curs[128];
  const int b = blockIdx.x;
  const int t = threadIdx.x;
  if (t < 128) h[t] = 0;
  __syncthreads();
  const int cnt = min(bcur[b], BCAP);
  const unsigned* be = bedge + (size_t)b * BCAP;
  for (int i = t; i < cnt; i += 256) atomicAdd(&h[(be[i] >> 17) & 127], 1);
  __syncthreads();
  int v = (t < 128) ? h[t] : 0;
  if (t < 128) sc[t] = v;
  __syncthreads();
  for (int d = 1; d < 128; d <<= 1) {
    int a = (t >= d && t < 128) ? sc[t - d] : 0;
    __syncthreads();
    if (t < 128) sc[t] += a;
    __syncthreads();
  }
  if (t < 128) {
    int o = bbase[b] + sc[t] - v;  // exclusive node offset
    int n = b * 128 + t;
    if (n < NN) off[n] = o;
    curs[t] = o;
  }
  __syncthreads();
  for (int i = t; i < cnt; i += 256) {
    unsigned u = be[i];
    int node = (u >> 17) & 127;
    int p = atomicAdd(&curs[node], 1);
    csr[p] = (int)(u & 0x1FFFF);
  }
}

// ---- pos prepack: [N][3] fp32 -> padded float4 (1 load/neighbor in layer1) -
__global__ __launch_bounds__(256) void k_pospack(const float* __restrict__ pos,
                                                 float4* __restrict__ pos4) {
  int n = blockIdx.x * 256 + threadIdx.x;
  if (n >= NN) return;
  pos4[n] = make_float4(pos[n * 3], pos[n * 3 + 1], pos[n * 3 + 2], 0.f);
}

// ------- weight pack: fp32 [k][n] -> fp16 in MFMA B-fragment order ----------
struct WPtrs { const float* w[9]; };
__global__ __launch_bounds__(256) void k_packw(WPtrs wp, f16* __restrict__ out) {
  int t = blockIdx.x * 256 + threadIdx.x;  // 9 * 16384
  int mat = t >> 14;
  int idx = t & 16383;
  int j = idx & 7;
  int lane = (idx >> 3) & 63;
  int ks = (idx >> 9) & 3;
  int nt = idx >> 11;
  int c16 = lane & 15, quad = lane >> 4;
  int k = ks * 32 + quad * 8 + j;
  int n = nt * 16 + c16;
  out[(size_t)mat * 16384 + idx] = (f16)wp.w[mat][k * CC + n];
}

// ---- FUSED layer 1: agg3 (thread-per-node, LDS) + node update (3 -> 128) ---
__global__ __launch_bounds__(256) void k_layer1(
    const int* __restrict__ off, const int* __restrict__ csr,
    const float4* __restrict__ pos4, const float* __restrict__ wl,
    const float* __restrict__ bl, const float* __restrict__ wr,
    const float* __restrict__ g, const float* __restrict__ be,
    const float* __restrict__ bm, const float* __restrict__ bv,
    f16* __restrict__ x) {
  __shared__ float sa[256][3];
  const int t = threadIdx.x;
  const int nbase = blockIdx.x * 256;
  {
    const int n = nbase + t;
    float a0 = 0.f, a1 = 0.f, a2 = 0.f;
    if (n < NN) {
      const int b = off[n], e = off[n + 1];
      int i = b;
      for (; i + 4 <= e; i += 4) {
        float4 p0 = pos4[csr[i]];
        float4 p1 = pos4[csr[i + 1]];
        float4 p2 = pos4[csr[i + 2]];
        float4 p3 = pos4[csr[i + 3]];
        a0 += (p0.x + p1.x) + (p2.x + p3.x);
        a1 += (p0.y + p1.y) + (p2.y + p3.y);
        a2 += (p0.z + p1.z) + (p2.z + p3.z);
      }
      for (; i < e; i++) {
        float4 p = pos4[csr[i]];
        a0 += p.x;
        a1 += p.y;
        a2 += p.z;
      }
      const float rd = 1.0f / fmaxf((float)(e - b), 1.0f);
      a0 *= rd;
      a1 *= rd;
      a2 *= rd;
    }
    sa[t][0] = a0;
    sa[t][1] = a1;
    sa[t][2] = a2;
  }
  __syncthreads();
  const int c = t & 127;
  const int np = t >> 7;  // node parity (uniform per wave)
  const float Wl0 = wl[c], Wl1 = wl[CC + c], Wl2 = wl[2 * CC + c];
  const float Wr0 = wr[c], Wr1 = wr[CC + c], Wr2 = wr[2 * CC + c];
  const float sc = g[c] * rsqrtf(bv[c] + 1e-5f);
  const float o0 = be[c] + (bl[c] - bm[c]) * sc;
  const int nend = min(nbase + 256, NN);
#pragma unroll 4
  for (int n = nbase + np; n < nend; n += 2) {
    const int ln = n - nbase;
    float4 p = pos4[n];
    float acc = sa[ln][0] * Wl0 + sa[ln][1] * Wl1 + sa[ln][2] * Wl2 +
                p.x * Wr0 + p.y * Wr1 + p.z * Wr2;
    x[(size_t)n * CC + c] = (f16)fmaxf(acc * sc + o0, 0.0f);
  }
}

// -------- aggregate (C=128): one wave per node, 16-deep load pipeline -------
__global__ __launch_bounds__(256) void k_aggregate(const int* __restrict__ off,
                                                   const int* __restrict__ csr,
                                                   const f16* __restrict__ x,
                                                   f16* __restrict__ agg) {
  const int n = blockIdx.x * 4 + (threadIdx.x >> 6);
  const int lane = threadIdx.x & 63;
  const int b = off[n], e = off[n + 1];
  float a0 = 0.f, a1 = 0.f;
  int i = b;
  // clean 16-deep blocks
  for (; i + 16 <= e; i += 16) {
    int sdx[16];
#pragma unroll
    for (int q = 0; q < 16; q++) sdx[q] = csr[i + q];
    f16x2 v[16];
#pragma unroll
    for (int q = 0; q < 16; q++)
      v[q] = *(const f16x2*)(x + (size_t)sdx[q] * CC + lane * 2);
#pragma unroll
    for (int q = 0; q < 16; q++) {
      a0 += (float)v[q][0];
      a1 += (float)v[q][1];
    }
  }
  // one predicated 16-block tail: clamp index (dup loads = same-addr L1 hits)
  const int lim = e - i;
  if (lim > 0) {
    int sdx[16];
#pragma unroll
    for (int q = 0; q < 16; q++) sdx[q] = csr[i + (q < lim ? q : lim - 1)];
    f16x2 v[16];
#pragma unroll
    for (int q = 0; q < 16; q++)
      v[q] = *(const f16x2*)(x + (size_t)sdx[q] * CC + lane * 2);
#pragma unroll
    for (int q = 0; q < 16; q++) {
      if (q < lim) {
        a0 += (float)v[q][0];
        a1 += (float)v[q][1];
      }
    }
  }
  const float rd = 1.0f / fmaxf((float)(e - b), 1.0f);
  f16x2 o;
  o[0] = (f16)(a0 * rd);
  o[1] = (f16)(a1 * rd);
  *(f16x2*)(agg + (size_t)n * CC + lane * 2) = o;
}

// ---- SAGE MFMA fp16 (128-row / 512-thread blocks): D = agg@wl + x@wr -------
__global__ __launch_bounds__(512) void k_sage_mfma(
    const f16* __restrict__ xin, f16* __restrict__ xout,
    const f16* __restrict__ agg, const f16* __restrict__ wl,
    const f16* __restrict__ wr, const float* __restrict__ bl,
    const float* __restrict__ g, const float* __restrict__ be,
    const float* __restrict__ bm, const float* __restrict__ bv) {
  const int lane = threadIdx.x & 63;
  const int wave = threadIdx.x >> 6;  // 0..7
  const int c16 = lane & 15;
  const int quad = lane >> 4;
  const int n0 = blockIdx.x * 128 + wave * 16;
  const int rowX = min(n0 + c16, NP - 1);  // last block can overshoot NP
  const int rowA = min(rowX, NN - 1);      // agg (in d_out) has NN rows
  const f16* px = xin + (size_t)rowX * CC + quad * 8;
  const f16* pa = agg + (size_t)rowA * CC + quad * 8;
  f32x4 acc[8];
#pragma unroll
  for (int t = 0; t < 8; t++) acc[t] = {0.f, 0.f, 0.f, 0.f};
#pragma unroll
  for (int ks = 0; ks < 4; ks++) {
    f16x8 Ax = *(const f16x8*)(px + ks * 32);
    f16x8 Aa = *(const f16x8*)(pa + ks * 32);
#pragma unroll
    for (int nt = 0; nt < 8; nt++) {
      const size_t wo = (size_t)((nt * 4 + ks) * 64 + lane) * 8;
      f16x8 Bl = *(const f16x8*)(wl + wo);
      f16x8 Br = *(const f16x8*)(wr + wo);
      acc[nt] = MFMA16(Aa, Bl, acc[nt]);
      acc[nt] = MFMA16(Ax, Br, acc[nt]);
    }
  }
#pragma unroll
  for (int nt = 0; nt < 8; nt++) {
    const int col = nt * 16 + c16;
    const float blc = bl[col];
    const float sc = g[col] * rsqrtf(bv[col] + 1e-5f);
    const float mm = bm[col];
    const float bb = be[col];
#pragma unroll
    for (int r = 0; r < 4; r++) {
      const int node = n0 + quad * 4 + r;
      if (node < NN) {
        float yv = fmaxf((acc[nt][r] + blc - mm) * sc + bb, 0.0f);
        xout[(size_t)node * CC + col] = (f16)yv;
      }
    }
  }
}

// -------- fused FC head (128-row / 512-thread): 3 chained GEMMs -------------
__global__ __launch_bounds__(512) void k_dense_fused(
    const f16* __restrict__ x, const f16* __restrict__ w1,
    const f16* __restrict__ w2, const f16* __restrict__ w3,
    const float* __restrict__ b1, const float* __restrict__ b2,
    const float* __restrict__ b3, float* __restrict__ out) {
  const int lane = threadIdx.x & 63;
  const int wave = threadIdx.x >> 6;  // 0..7
  const int c16 = lane & 15;
  const int quad = lane >> 4;
  const int n0 = blockIdx.x * 128 + wave * 16;
  const int lrow = wave * 16;
  __shared__ f16 sh[128][136];  // +8 pad

  f32x4 acc[8];
#pragma unroll
  for (int t = 0; t < 8; t++) acc[t] = {0.f, 0.f, 0.f, 0.f};
  const int rowX = min(n0 + c16, NP - 1);
  const f16* px = x + (size_t)rowX * CC + quad * 8;
#pragma unroll
  for (int ks = 0; ks < 4; ks++) {
    f16x8 Ax = *(const f16x8*)(px + ks * 32);
#pragma unroll
    for (int nt = 0; nt < 8; nt++) {
      f16x8 B = *(const f16x8*)(w1 + (size_t)((nt * 4 + ks) * 64 + lane) * 8);
      acc[nt] = MFMA16(Ax, B, acc[nt]);
    }
  }
#pragma unroll
  for (int nt = 0; nt < 8; nt++) {
    const int col = nt * 16 + c16;
    const float bc = b1[col];
#pragma unroll
    for (int r = 0; r < 4; r++)
      sh[lrow + quad * 4 + r][col] = (f16)fmaxf(acc[nt][r] + bc, 0.0f);
  }
  // FC2 (wave-local rows, no barrier needed)
#pragma unroll
  for (int t = 0; t < 8; t++) acc[t] = {0.f, 0.f, 0.f, 0.f};
#pragma unroll
  for (int ks = 0; ks < 4; ks++) {
    f16x8 Ax = *(const f16x8*)&sh[lrow + c16][ks * 32 + quad * 8];
#pragma unroll
    for (int nt = 0; nt < 8; nt++) {
      f16x8 B = *(const f16x8*)(w2 + (size_t)((nt * 4 + ks) * 64 + lane) * 8);
      acc[nt] = MFMA16(Ax, B, acc[nt]);
    }
  }
#pragma unroll
  for (int nt = 0; nt < 8; nt++) {
    const int col = nt * 16 + c16;
    const float bc = b2[col];
#pragma unroll
    for (int r = 0; r < 4; r++)
      sh[lrow + quad * 4 + r][col] = (f16)(acc[nt][r] + bc);
  }
  // FC3 -> out (fp32)
#pragma unroll
  for (int t = 0; t < 8; t++) acc[t] = {0.f, 0.f, 0.f, 0.f};
#pragma unroll
  for (int ks = 0; ks < 4; ks++) {
    f16x8 Ax = *(const f16x8*)&sh[lrow + c16][ks * 32 + quad * 8];
#pragma unroll
    for (int nt = 0; nt < 8; nt++) {
      f16x8 B = *(const f16x8*)(w3 + (size_t)((nt * 4 + ks) * 64 + lane) * 8);
      acc[nt] = MFMA16(Ax, B, acc[nt]);
    }
  }
#pragma unroll
  for (int nt = 0; nt < 8; nt++) {
    const int col = nt * 16 + c16;
    const float bc = b3[col];
#pragma unroll
    for (int r = 0; r < 4; r++) {
      const int node = n0 + quad * 4 + r;
      if (node < NN) out[(size_t)node * CC + col] = acc[nt][r] + bc;
    }
  }
}

extern "C" void kernel_launch(void* const* d_in, const int* in_sizes, int n_in,
                              void* d_out, int out_size, void* d_ws,
                              size_t ws_size, hipStream_t stream) {
  const float* pos = (const float*)d_in[0];
  const int* ei = (const int*)d_in[1];
  const int* src = ei;
  const int* dst = ei + EE;
  auto P = [&](int i) { return (const float*)d_in[i]; };

  // ws: bcur[NBK] | bbase[NBK] | off[NN+4 pad] | bedge[NBK*BCAP] | csr[E] |
  //     wp16 | xa | xb   (~62.5 MB). bedge is dead after k_bfill2 -> its
  //     space (16B-aligned) is reused for pos4[NN] (1.6 MB).
  int* bcur = (int*)d_ws;
  int* bbase = bcur + NBK;
  int* off = bbase + NBK;
  unsigned* bedge = (unsigned*)(off + NN + 4);  // +4 keeps bedge 16B-aligned
  int* csr = (int*)(bedge + (size_t)NBK * BCAP);
  f16* wp16 = (f16*)(csr + EE);
  f16* xa = wp16 + 9 * 16384;
  f16* xb = xa + (size_t)NP * CC;

  float4* pos4 = (float4*)bedge;  // reuse (dead after k_bfill2)

  f16* agg = (f16*)d_out;  // scratch until the final dense overwrites d_out

  hipMemsetAsync(bcur, 0, NBK * sizeof(int), stream);

  // CSR build: partition -> bucket scan -> per-bucket offsets+fill
  k_part<<<(EE / 4 + 4095) / 4096, 1024, 0, stream>>>(src, dst, bcur, bedge);
  k_bscan<<<1, 1024, 0, stream>>>(bcur, bbase, off);
  k_bfill2<<<NBK, 256, 0, stream>>>(bcur, bbase, bedge, off, csr);

  // pos prepack (into the now-dead bedge region)
  k_pospack<<<(NN + 255) / 256, 256, 0, stream>>>(pos, pos4);

  WPtrs wp;
  const int wsrc[9] = {9, 11, 16, 18, 23, 25, 30, 32, 34};
  for (int i = 0; i < 9; i++) wp.w[i] = P(wsrc[i]);
  k_packw<<<(9 * 16384) / 256, 256, 0, stream>>>(wp, wp16);

  // layer 1 (Cin=3), fused aggregate + node update
  k_layer1<<<(NN + 255) / 256, 256, 0, stream>>>(
      off, csr, pos4, P(2), P(3), P(4), P(5), P(6), P(7), P(8), xa);

  // layers 2..4: ping-pong xa -> xb -> xa -> xb
  const f16* xi = xa;
  f16* xo = xb;
  for (int l = 1; l < 4; l++) {
    int base = 2 + 7 * l;
    int mat = (l - 1) * 2;
    k_aggregate<<<NN / 4, 256, 0, stream>>>(off, csr, xi, agg);
    k_sage_mfma<<<NBS, 512, 0, stream>>>(xi, xo, agg,
                                         wp16 + (size_t)mat * 16384,
                                         wp16 + (size_t)(mat + 1) * 16384,
                                         P(base + 1), P(base + 3), P(base + 4),
                                         P(base + 5), P(base + 6));
    const f16* t = xi;
    xi = xo;
    xo = (f16*)t;
  }

  // fused FC head
  k_dense_fused<<<NBS, 512, 0, stream>>>(xi, wp16 + (size_t)6 * 16384,
                                         wp16 + (size_t)7 * 16384,
                                         wp16 + (size_t)8 * 16384, P(31), P(33),
                                         P(35), (float*)d_out);
}